// Round 10
// baseline (250.914 us; speedup 1.0000x reference)
//
#include <hip/hip_runtime.h>

typedef unsigned short u16;
typedef float f32x4 __attribute__((ext_vector_type(4)));
typedef __bf16 bf16x8 __attribute__((ext_vector_type(8)));

__device__ __forceinline__ u16 f2bf(float f) {
  union { float f; unsigned u; } v; v.f = f;
  unsigned r = (v.u + 0x7fffu + ((v.u >> 16) & 1u)) >> 16;
  return (u16)r;
}
__device__ __forceinline__ float bf2f(u16 h) {
  union { unsigned u; float f; } v; v.u = ((unsigned)h) << 16; return v.f;
}
// pack two f32 -> one u32 of 2x bf16 (lo=a, hi=b) in pure C (no ISA assumption)
__device__ __forceinline__ unsigned pack2bf(float a, float b) {
  return ((unsigned)f2bf(b) << 16) | (unsigned)f2bf(a);
}

#define LOG2E 1.4426950408889634f

// ---------------------------------------------------------------- cast weights
__global__ __launch_bounds__(256) void cast_w_kernel(
    const float* __restrict__ wq, const float* __restrict__ wk,
    const float* __restrict__ wv, const float* __restrict__ wg,
    const float* __restrict__ wo, u16* __restrict__ wcat, u16* __restrict__ wobf)
{
  int idx = blockIdx.x * 256 + threadIdx.x;   // 320 blocks -> 81920 threads
  int e = idx * 4;                            // 4 floats each
  int row = e >> 8;
  int col = e & 255;
  const float* src = (row < 256)  ? (wq + (size_t)row * 256)
                   : (row < 512)  ? (wk + (size_t)(row - 256) * 256)
                   : (row < 768)  ? (wv + (size_t)(row - 512) * 256)
                   : (row < 1024) ? (wg + (size_t)(row - 768) * 256)
                                  : (wo + (size_t)(row - 1024) * 256);
  float4 v = *(const float4*)(src + col);
  ushort4 o;
  o.x = f2bf(v.x); o.y = f2bf(v.y); o.z = f2bf(v.z); o.w = f2bf(v.w);
  if (row < 1024) *(ushort4*)(wcat + e) = o;
  else            *(ushort4*)(wobf + (e - 262144)) = o;
}

// ---------------------------------------------------------------- LN(msa)->bf16
__global__ __launch_bounds__(256) void ln_msa_kernel(
    const float* __restrict__ x, const float* __restrict__ sc,
    const float* __restrict__ bi, u16* __restrict__ mo)
{
  const int row  = blockIdx.x * 4 + (threadIdx.x >> 6);
  const int lane = threadIdx.x & 63;
  const float4 v = *(const float4*)(x + (size_t)row * 256 + lane * 4);
  float s = v.x + v.y + v.z + v.w;
  #pragma unroll
  for (int off = 1; off < 64; off <<= 1) s += __shfl_xor(s, off);
  const float mu = s * 0.00390625f;
  const float d0 = v.x - mu, d1 = v.y - mu, d2 = v.z - mu, d3 = v.w - mu;
  float vs = d0*d0 + d1*d1 + d2*d2 + d3*d3;
  #pragma unroll
  for (int off = 1; off < 64; off <<= 1) vs += __shfl_xor(vs, off);
  const float rstd = rsqrtf(vs * 0.00390625f + 1e-5f);
  const float4 scv = *(const float4*)(sc + lane * 4);
  const float4 biv = *(const float4*)(bi + lane * 4);
  ushort4 o;
  o.x = f2bf(d0 * rstd * scv.x + biv.x);
  o.y = f2bf(d1 * rstd * scv.y + biv.y);
  o.z = f2bf(d2 * rstd * scv.z + biv.z);
  o.w = f2bf(d3 * rstd * scv.w + biv.w);
  *(ushort4*)(mo + (size_t)row * 256 + lane * 4) = o;
}

// ------------------------------------------- LN(pair) + einsum('ijc,hc->hij')
// Writes bias NATURAL layout, bf16, pre-scaled by log2(e): biasQ[h][i=q][j=key]
__global__ __launch_bounds__(256) void ln_pair_bias_kernel(
    const float* __restrict__ pair, const float* __restrict__ sc,
    const float* __restrict__ bi, const float* __restrict__ wb,
    u16* __restrict__ biasQ)
{
  __shared__ float swb[1024];
  #pragma unroll
  for (int i = 0; i < 4; ++i) swb[i * 256 + threadIdx.x] = wb[i * 256 + threadIdx.x];
  __syncthreads();
  const int ij   = blockIdx.x * 4 + (threadIdx.x >> 6);   // 0..65535
  const int lane = threadIdx.x & 63;
  const float2 v = *(const float2*)(pair + (size_t)ij * 128 + lane * 2);
  float s = v.x + v.y;
  #pragma unroll
  for (int off = 1; off < 64; off <<= 1) s += __shfl_xor(s, off);
  const float mu = s * 0.0078125f;
  const float d0 = v.x - mu, d1 = v.y - mu;
  float vs = d0*d0 + d1*d1;
  #pragma unroll
  for (int off = 1; off < 64; off <<= 1) vs += __shfl_xor(vs, off);
  const float rstd = rsqrtf(vs * 0.0078125f + 1e-5f);
  const float2 scv = *(const float2*)(sc + lane * 2);
  const float2 biv = *(const float2*)(bi + lane * 2);
  const float z0 = d0 * rstd * scv.x + biv.x;
  const float z1 = d1 * rstd * scv.y + biv.y;
  float a[8];
  #pragma unroll
  for (int hh = 0; hh < 8; ++hh)
    a[hh] = z0 * swb[hh * 128 + lane * 2] + z1 * swb[hh * 128 + lane * 2 + 1];
  #pragma unroll
  for (int off = 1; off < 64; off <<= 1) {
    #pragma unroll
    for (int hh = 0; hh < 8; ++hh) a[hh] += __shfl_xor(a[hh], off);
  }
  if (lane == 0) {
    const int i = ij >> 8, j = ij & 255;
    #pragma unroll
    for (int hh = 0; hh < 8; ++hh) biasQ[hh * 65536 + i * 256 + j] = f2bf(a[hh] * LOG2E);
  }
}

// --------------------- barrier-free direct-load GEMM (TLP-hiding, no LDS)
// C(M x 64*NCG) = A(M x 256) * B^T. Per block: 128 rows x 64 cols, 4 waves.
// A and B fragments load DIRECTLY global->VGPR (B is L2/L3-resident; all 4
// waves read identical B addresses -> L1 broadcast). Zero barriers, zero LDS:
// occupancy VGPR-limited, latency hidden by wave count (m114 overlap).
// K-loop unroll 2 = depth-2 pipeline without VGPR blowup.
// MFMA operands swapped (mfma(b,a)) -> lane owns 4 consecutive output cols
// (HW-verified layout, rounds 6-7). EPI 0: qkvg epilogue; EPI 1: residual.
template<int EPI, int NCG>
__global__ __launch_bounds__(256) void gemm_direct(
    const u16* __restrict__ A, const u16* __restrict__ B,
    u16* __restrict__ Cbf, const float* __restrict__ bgate,
    float* __restrict__ Cf, const float* __restrict__ msa,
    const u16* __restrict__ gate, const float* __restrict__ bout)
{
  const int tid = threadIdx.x, lane = tid & 63, w = tid >> 6;
  const int g = lane >> 4, r15 = lane & 15;
  const int xcd = blockIdx.x & 7;
  const int lb = blockIdx.x >> 3;
  const int cg = lb % NCG;                 // col-group (fast -> A L2 reuse/XCD)
  const int rt = lb / NCG;                 // row tile 0..31 within XCD
  const int brow = (xcd * 32 + rt) * 128;
  const int bcol = cg * 64;

  const size_t arow0 = (size_t)brow + w * 32 + r15;

  f32x4 acc[2][4] = {};
  #pragma unroll 2
  for (int kk = 0; kk < 8; ++kk) {
    bf16x8 af0 = *(const bf16x8*)(A + (arow0     ) * 256 + kk * 32 + g * 8);
    bf16x8 af1 = *(const bf16x8*)(A + (arow0 + 16) * 256 + kk * 32 + g * 8);
    bf16x8 bfr[4];
    #pragma unroll
    for (int n = 0; n < 4; ++n)
      bfr[n] = *(const bf16x8*)(B + (size_t)(bcol + n * 16 + r15) * 256 + kk * 32 + g * 8);
    #pragma unroll
    for (int n = 0; n < 4; ++n)
      acc[0][n] = __builtin_amdgcn_mfma_f32_16x16x32_bf16(bfr[n], af0, acc[0][n], 0, 0, 0);
    #pragma unroll
    for (int n = 0; n < 4; ++n)
      acc[1][n] = __builtin_amdgcn_mfma_f32_16x16x32_bf16(bfr[n], af1, acc[1][n], 0, 0, 0);
  }

  // hoisted per-lane epilogue constants (4 consecutive cols per lane)
  f32x4 gb4[4], bo4[4];
  if (EPI == 0 && cg >= (NCG * 3) / 4) {
    #pragma unroll
    for (int n = 0; n < 4; ++n)
      gb4[n] = *(const f32x4*)(bgate + bcol - 768 + n * 16 + g * 4);
  }
  if (EPI == 1) {
    #pragma unroll
    for (int n = 0; n < 4; ++n)
      bo4[n] = *(const f32x4*)(bout + bcol + n * 16 + g * 4);
  }

  // vectorized epilogue: lane owns C[row = brow+w*32+m*16+r15]
  //                                [cols = bcol+n*16+g*4 .. +3]
  #pragma unroll
  for (int m = 0; m < 2; ++m) {
    const size_t row = (size_t)brow + w * 32 + m * 16 + r15;
    #pragma unroll
    for (int n = 0; n < 4; ++n) {
      const int col = bcol + n * 16 + g * 4;
      f32x4 v = acc[m][n];
      if (EPI == 0) {
        if (cg < NCG / 4) {
          #pragma unroll
          for (int rr = 0; rr < 4; ++rr) v[rr] *= 0.17677669529663687f * LOG2E;
        } else if (cg >= (NCG * 3) / 4) {
          #pragma unroll
          for (int rr = 0; rr < 4; ++rr)
            v[rr] = 1.0f / (1.0f + __expf(-(v[rr] + gb4[n][rr])));
        }
        ushort4 o;
        o.x = f2bf(v[0]); o.y = f2bf(v[1]); o.z = f2bf(v[2]); o.w = f2bf(v[3]);
        *(ushort4*)(Cbf + row * 1024 + col) = o;
      } else {
        ushort4 gg = *(const ushort4*)(gate + row * 1024 + col);
        f32x4 ms = *(const f32x4*)(msa + row * 256 + col);
        f32x4 o;
        o[0] = ms[0] + bf2f(gg.x) * (v[0] + bo4[n][0]);
        o[1] = ms[1] + bf2f(gg.y) * (v[1] + bo4[n][1]);
        o[2] = ms[2] + bf2f(gg.z) * (v[2] + bo4[n][2]);
        o[3] = ms[3] + bf2f(gg.w) * (v[3] + bo4[n][3]);
        *(f32x4*)(Cf + row * 256 + col) = o;
      }
    }
  }
}

// --------------------------------------------------------- attention
// 2048 blocks, XCD-aware: h = blk&7 (bias/K/V L2-resident per XCD).
// Block = 128 q rows, 4 waves x 32 q. Swapped QK^T (mfma(K,Q) -> S^T: lane
// holds q=r15, keys at (g,reg)) so P stays IN REGISTERS: pure-C RNE packing
// (pack2bf) builds the PV A-operand directly; V's LDS key order is permuted at
// staging to match (key<->k-slot mapping inside the MFMA is a shared bijection).
// No P LDS tile, no barriers in the loop, lane-local softmax denominator.
__global__ __launch_bounds__(256) void attn_kernel(
    const u16* __restrict__ qkvg, const u16* __restrict__ biasQ,
    u16* __restrict__ attn_out)
{
  __shared__ u16 sVt[32 * 264];      // V^T, padded rows, permuted key order
  const int blk = blockIdx.x;
  const int h = blk & 7;             // head == XCD
  const int idx2 = blk >> 3;
  const int qh = idx2 & 1;
  const int b = idx2 >> 1;
  const int tid = threadIdx.x, lane = tid & 63, w = tid >> 6;
  const int g = lane >> 4, r15 = lane & 15;
  const size_t rowbase = (size_t)b * 256;
  const int qbase = qh * 128;

  // stage V^T; key tid stored at permuted column pos so that position
  // kb*32 + g*8 + j holds key kb*32 + (j>>2)*16 + g*4 + (j&3) — the exact
  // register order of the in-register P fragment below.
  {
    const int nl = (tid >> 4) & 3, q4 = tid & 15;
    const int pos = (tid >> 6) * 64 + (nl >> 1) * 32 + (q4 >> 2) * 8 + (nl & 1) * 4 + (q4 & 3);
    const uint4* vr4 = (const uint4*)(qkvg + (rowbase + tid) * 1024 + 512 + h * 32);
    #pragma unroll
    for (int c = 0; c < 4; ++c) {
      uint4 vv = vr4[c];
      unsigned uu[4] = {vv.x, vv.y, vv.z, vv.w};
      #pragma unroll
      for (int p = 0; p < 4; ++p) {
        sVt[(c * 8 + p * 2    ) * 264 + pos] = (u16)(uu[p] & 0xffffu);
        sVt[(c * 8 + p * 2 + 1) * 264 + pos] = (u16)(uu[p] >> 16);
      }
    }
  }

  const int qrel0 = qbase + w * 32 + r15;
  // Q fragments straight from global (already scaled by log2e/sqrt(32))
  bf16x8 qf[2];
  #pragma unroll
  for (int m = 0; m < 2; ++m)
    qf[m] = *(const bf16x8*)(qkvg + (rowbase + qrel0 + m * 16) * 1024 + h * 32 + g * 8);
  __syncthreads();

  f32x4 oacc[2][2] = {};
  float lrun[2] = {0.f, 0.f};
  const u16* biasH = biasQ + (size_t)h * 65536;

  // prefetch jb=0 K fragments + bias (bf16, 8B per frag)
  bf16x8 kf[4];
  ushort4 bvu[2][4];
  #pragma unroll
  for (int n = 0; n < 4; ++n)
    kf[n] = *(const bf16x8*)(qkvg + (rowbase + n * 16 + r15) * 1024 + 256 + h * 32 + g * 8);
  #pragma unroll
  for (int m = 0; m < 2; ++m)
    #pragma unroll
    for (int n = 0; n < 4; ++n)
      bvu[m][n] = *(const ushort4*)(biasH + (size_t)(qrel0 + m * 16) * 256 + n * 16 + g * 4);

  for (int jb = 0; jb < 4; ++jb) {
    // S^T = K.Q^T: lane holds S[q = qrel0 + m*16][key = jb*64 + n*16 + g*4 + rr]
    f32x4 s[2][4];
    #pragma unroll
    for (int m = 0; m < 2; ++m) {
      #pragma unroll
      for (int n = 0; n < 4; ++n) {
        f32x4 z = {0.f, 0.f, 0.f, 0.f};
        s[m][n] = __builtin_amdgcn_mfma_f32_16x16x32_bf16(kf[n], qf[m], z, 0, 0, 0);
        const u16* bb = (const u16*)&bvu[m][n];
        #pragma unroll
        for (int rr = 0; rr < 4; ++rr) s[m][n][rr] += bf2f(bb[rr]);
      }
    }
    // prefetch next jb (loads overlap exp+PV below)
    if (jb < 3) {
      const int j1 = jb + 1;
      #pragma unroll
      for (int n = 0; n < 4; ++n)
        kf[n] = *(const bf16x8*)(qkvg + (rowbase + j1 * 64 + n * 16 + r15) * 1024 + 256 + h * 32 + g * 8);
      #pragma unroll
      for (int m = 0; m < 2; ++m)
        #pragma unroll
        for (int n = 0; n < 4; ++n)
          bvu[m][n] = *(const ushort4*)(biasH + (size_t)(qrel0 + m * 16) * 256 + j1 * 64 + n * 16 + g * 4);
    }
    // P = exp2(S): lane-local denominator (all 16 values belong to q=r15)
    unsigned pk[2][4][2];
    #pragma unroll
    for (int m = 0; m < 2; ++m) {
      #pragma unroll
      for (int n = 0; n < 4; ++n) {
        #pragma unroll
        for (int rr = 0; rr < 4; ++rr) {
          float p = __builtin_amdgcn_exp2f(s[m][n][rr]);
          s[m][n][rr] = p;
          lrun[m] += p;
        }
        pk[m][n][0] = pack2bf(s[m][n][0], s[m][n][1]);
        pk[m][n][1] = pack2bf(s[m][n][2], s[m][n][3]);
      }
    }
    // PV: P already in A-fragment layout; V read in matching permuted order
    #pragma unroll
    for (int kb = 0; kb < 2; ++kb) {
      bf16x8 vt[2];
      #pragma unroll
      for (int nd = 0; nd < 2; ++nd)
        vt[nd] = *(const bf16x8*)&sVt[(nd * 16 + r15) * 264 + jb * 64 + kb * 32 + g * 8];
      #pragma unroll
      for (int m = 0; m < 2; ++m) {
        union { unsigned u[4]; bf16x8 v; } pu;
        pu.u[0] = pk[m][2 * kb][0];     pu.u[1] = pk[m][2 * kb][1];
        pu.u[2] = pk[m][2 * kb + 1][0]; pu.u[3] = pk[m][2 * kb + 1][1];
        #pragma unroll
        for (int nd = 0; nd < 2; ++nd)
          oacc[m][nd] = __builtin_amdgcn_mfma_f32_16x16x32_bf16(pu.v, vt[nd], oacc[m][nd], 0, 0, 0);
      }
    }
  }

  // denominator: reduce across the 4 g-groups (bits 4,5), then redistribute
  // to the C-layout q index (g*4+rr) via one shuffle per rr.
  #pragma unroll
  for (int m = 0; m < 2; ++m) {
    float l = lrun[m];
    l += __shfl_xor(l, 16);
    l += __shfl_xor(l, 32);
    const float inv = 1.0f / l;
    #pragma unroll
    for (int rr = 0; rr < 4; ++rr) {
      const float invq = __shfl(inv, g * 4 + rr);
      const size_t qrow = rowbase + qbase + w * 32 + m * 16 + g * 4 + rr;
      #pragma unroll
      for (int nd = 0; nd < 2; ++nd)
        attn_out[qrow * 256 + h * 32 + nd * 16 + r15] = f2bf(oacc[m][nd][rr] * invq);
    }
  }
}

// ------------------------------------------------------------------- launcher
extern "C" void kernel_launch(void* const* d_in, const int* in_sizes, int n_in,
                              void* d_out, int out_size, void* d_ws, size_t ws_size,
                              hipStream_t stream)
{
  (void)in_sizes; (void)n_in; (void)out_size; (void)ws_size;
  const float* msa        = (const float*)d_in[0];
  const float* pair       = (const float*)d_in[1];
  const float* ln_m_scale = (const float*)d_in[2];
  const float* ln_m_bias  = (const float*)d_in[3];
  const float* ln_z_scale = (const float*)d_in[4];
  const float* ln_z_bias  = (const float*)d_in[5];
  const float* w_q        = (const float*)d_in[6];
  const float* w_k        = (const float*)d_in[7];
  const float* w_v        = (const float*)d_in[8];
  const float* w_b        = (const float*)d_in[9];
  const float* w_out      = (const float*)d_in[10];
  const float* b_out      = (const float*)d_in[11];
  const float* w_gate     = (const float*)d_in[12];
  const float* b_gate     = (const float*)d_in[13];

  char* ws = (char*)d_ws;
  u16*   m_bf   = (u16*)(ws);                    // 32768*256 bf16   = 16 MB
  u16*   wcat   = (u16*)(ws + 16777216);         // 1024*256 bf16    = 0.5 MB
  u16*   wobf   = (u16*)(ws + 17301504);         // 256*256 bf16
  u16*   qkvg   = (u16*)(ws + 17432576);         // 32768*1024 bf16  = 64 MB
  u16*   biasQ  = (u16*)(ws + 84541440);         // 8*256*256 bf16   = 1 MB
  u16*   attn_o = (u16*)(ws + 86638592);         // 32768*256 bf16   = 16 MB
  float* out = (float*)d_out;

  cast_w_kernel<<<dim3(320), dim3(256), 0, stream>>>(w_q, w_k, w_v, w_gate, w_out, wcat, wobf);
  ln_msa_kernel<<<dim3(8192), dim3(256), 0, stream>>>(msa, ln_m_scale, ln_m_bias, m_bf);
  ln_pair_bias_kernel<<<dim3(16384), dim3(256), 0, stream>>>(pair, ln_z_scale, ln_z_bias, w_b, biasQ);
  gemm_direct<0, 16><<<dim3(4096), dim3(256), 0, stream>>>(m_bf, wcat, qkvg, b_gate,
                                                           nullptr, nullptr, nullptr, nullptr);
  attn_kernel<<<dim3(2048), dim3(256), 0, stream>>>(qkvg, biasQ, attn_o);
  gemm_direct<1, 4><<<dim3(1024), dim3(256), 0, stream>>>(attn_o, wobf, nullptr, nullptr,
                                                          out, msa, qkvg + 768, b_out);
}

// Round 11
// 200.257 us; speedup vs baseline: 1.2530x; 1.2530x over previous
//
#include <hip/hip_runtime.h>

typedef unsigned short u16;
typedef float f32x4 __attribute__((ext_vector_type(4)));
typedef __bf16 bf16x8 __attribute__((ext_vector_type(8)));

__device__ __forceinline__ u16 f2bf(float f) {
  union { float f; unsigned u; } v; v.f = f;
  unsigned r = (v.u + 0x7fffu + ((v.u >> 16) & 1u)) >> 16;
  return (u16)r;
}
__device__ __forceinline__ float bf2f(u16 h) {
  union { unsigned u; float f; } v; v.u = ((unsigned)h) << 16; return v.f;
}
// pack two f32 -> one u32 of 2x bf16 (lo=a, hi=b) in pure C (no ISA assumption)
__device__ __forceinline__ unsigned pack2bf(float a, float b) {
  return ((unsigned)f2bf(b) << 16) | (unsigned)f2bf(a);
}

#define GLOAD16(gp, lp)                                                        \
  __builtin_amdgcn_global_load_lds(                                            \
      (const __attribute__((address_space(1))) void*)(gp),                     \
      (__attribute__((address_space(3))) void*)(lp), 16, 0, 0)

#define LOG2E 1.4426950408889634f

// ---------------------------------------------------------------- cast weights
__global__ __launch_bounds__(256) void cast_w_kernel(
    const float* __restrict__ wq, const float* __restrict__ wk,
    const float* __restrict__ wv, const float* __restrict__ wg,
    const float* __restrict__ wo, u16* __restrict__ wcat, u16* __restrict__ wobf)
{
  int idx = blockIdx.x * 256 + threadIdx.x;   // 320 blocks -> 81920 threads
  int e = idx * 4;                            // 4 floats each
  int row = e >> 8;
  int col = e & 255;
  const float* src = (row < 256)  ? (wq + (size_t)row * 256)
                   : (row < 512)  ? (wk + (size_t)(row - 256) * 256)
                   : (row < 768)  ? (wv + (size_t)(row - 512) * 256)
                   : (row < 1024) ? (wg + (size_t)(row - 768) * 256)
                                  : (wo + (size_t)(row - 1024) * 256);
  float4 v = *(const float4*)(src + col);
  ushort4 o;
  o.x = f2bf(v.x); o.y = f2bf(v.y); o.z = f2bf(v.z); o.w = f2bf(v.w);
  if (row < 1024) *(ushort4*)(wcat + e) = o;
  else            *(ushort4*)(wobf + (e - 262144)) = o;
}

// ---------------------------------------------------------------- LN(msa)->bf16
__global__ __launch_bounds__(256) void ln_msa_kernel(
    const float* __restrict__ x, const float* __restrict__ sc,
    const float* __restrict__ bi, u16* __restrict__ mo)
{
  const int row  = blockIdx.x * 4 + (threadIdx.x >> 6);
  const int lane = threadIdx.x & 63;
  const float4 v = *(const float4*)(x + (size_t)row * 256 + lane * 4);
  float s = v.x + v.y + v.z + v.w;
  #pragma unroll
  for (int off = 1; off < 64; off <<= 1) s += __shfl_xor(s, off);
  const float mu = s * 0.00390625f;
  const float d0 = v.x - mu, d1 = v.y - mu, d2 = v.z - mu, d3 = v.w - mu;
  float vs = d0*d0 + d1*d1 + d2*d2 + d3*d3;
  #pragma unroll
  for (int off = 1; off < 64; off <<= 1) vs += __shfl_xor(vs, off);
  const float rstd = rsqrtf(vs * 0.00390625f + 1e-5f);
  const float4 scv = *(const float4*)(sc + lane * 4);
  const float4 biv = *(const float4*)(bi + lane * 4);
  ushort4 o;
  o.x = f2bf(d0 * rstd * scv.x + biv.x);
  o.y = f2bf(d1 * rstd * scv.y + biv.y);
  o.z = f2bf(d2 * rstd * scv.z + biv.z);
  o.w = f2bf(d3 * rstd * scv.w + biv.w);
  *(ushort4*)(mo + (size_t)row * 256 + lane * 4) = o;
}

// ------------------------------------------- LN(pair) + einsum('ijc,hc->hij')
// Writes bias NATURAL layout, bf16, pre-scaled by log2(e): biasQ[h][i=q][j=key]
__global__ __launch_bounds__(256) void ln_pair_bias_kernel(
    const float* __restrict__ pair, const float* __restrict__ sc,
    const float* __restrict__ bi, const float* __restrict__ wb,
    u16* __restrict__ biasQ)
{
  __shared__ float swb[1024];
  #pragma unroll
  for (int i = 0; i < 4; ++i) swb[i * 256 + threadIdx.x] = wb[i * 256 + threadIdx.x];
  __syncthreads();
  const int ij   = blockIdx.x * 4 + (threadIdx.x >> 6);   // 0..65535
  const int lane = threadIdx.x & 63;
  const float2 v = *(const float2*)(pair + (size_t)ij * 128 + lane * 2);
  float s = v.x + v.y;
  #pragma unroll
  for (int off = 1; off < 64; off <<= 1) s += __shfl_xor(s, off);
  const float mu = s * 0.0078125f;
  const float d0 = v.x - mu, d1 = v.y - mu;
  float vs = d0*d0 + d1*d1;
  #pragma unroll
  for (int off = 1; off < 64; off <<= 1) vs += __shfl_xor(vs, off);
  const float rstd = rsqrtf(vs * 0.0078125f + 1e-5f);
  const float2 scv = *(const float2*)(sc + lane * 2);
  const float2 biv = *(const float2*)(bi + lane * 2);
  const float z0 = d0 * rstd * scv.x + biv.x;
  const float z1 = d1 * rstd * scv.y + biv.y;
  float a[8];
  #pragma unroll
  for (int hh = 0; hh < 8; ++hh)
    a[hh] = z0 * swb[hh * 128 + lane * 2] + z1 * swb[hh * 128 + lane * 2 + 1];
  #pragma unroll
  for (int off = 1; off < 64; off <<= 1) {
    #pragma unroll
    for (int hh = 0; hh < 8; ++hh) a[hh] += __shfl_xor(a[hh], off);
  }
  if (lane == 0) {
    const int i = ij >> 8, j = ij & 255;
    #pragma unroll
    for (int hh = 0; hh < 8; ++hh) biasQ[hh * 65536 + i * 256 + j] = f2bf(a[hh] * LOG2E);
  }
}

// ----------------------------------------------- B-stationary small-K GEMM
// (r4-verbatim structure: the 64.5 µs champion.) B tile (64 cols x 256 K =
// 32 KB) staged once via swizzled global_load_lds; UNITS row-tiles of 128 rows,
// A frags direct global->VGPR (u=0 issued before the single barrier). XCD-aware:
// cg fast-varying within an XCD so its A slice (4096 rows) is L2/L3-local.
// EPI 0: qkvg epilogue (scale q by log2e/sqrt32, sigmoid gate); EPI 1: residual
template<int EPI, int NCG, int UNITS>
__global__ __launch_bounds__(256) void gemm_bstat(
    const u16* __restrict__ A, const u16* __restrict__ B,
    u16* __restrict__ Cbf, const float* __restrict__ bgate,
    float* __restrict__ Cf, const float* __restrict__ msa,
    const u16* __restrict__ gate, const float* __restrict__ bout)
{
  __shared__ u16 sB[64 * 256];   // 32 KB, XOR-swizzled within 128B groups
  const int tid = threadIdx.x, lane = tid & 63, w = tid >> 6;
  const int g = lane >> 4, r15 = lane & 15;
  const int x = blockIdx.x & 7;           // XCD
  const int j = blockIdx.x >> 3;
  const int cg = j % NCG;                 // col-group (fast-varying on an XCD)
  const int rpl = j / NCG;                // local row-group on this XCD
  const int bcol = cg * 64;

  // stage B tile; source pre-swizzled so linear LDS dest + XOR read match
  #pragma unroll
  for (int i = 0; i < 8; ++i) {
    int c = i * 256 + tid;                // chunk 0..2047 (16B each)
    int col = c >> 5, s = c & 31;
    int lc = (s & 24) | ((s ^ col) & 7);  // logical chunk stored at slot s
    GLOAD16(B + (size_t)(bcol + col) * 256 + lc * 8, &sB[c * 8]);
  }

  // hoisted epilogue constants
  float gb[4] = {0.f, 0.f, 0.f, 0.f};
  if (EPI == 0 && cg >= (NCG * 3) / 4) {
    #pragma unroll
    for (int n = 0; n < 4; ++n) gb[n] = bgate[bcol - 768 + n * 16 + r15];
  }
  float bo[4] = {0.f, 0.f, 0.f, 0.f};
  if (EPI == 1) {
    #pragma unroll
    for (int n = 0; n < 4; ++n) bo[n] = bout[bcol + n * 16 + r15];
  }

  for (int rt = 0; rt < UNITS; ++rt) {
    const size_t brow = ((size_t)(x * 32) + rpl * UNITS + rt) * 128;
    // A fragments direct from global (rt=0 loads issued before the barrier:
    // latency hides under the B-stage vmcnt drain)
    bf16x8 af[2][8];
    #pragma unroll
    for (int m = 0; m < 2; ++m) {
      const size_t arow = brow + w * 32 + m * 16 + r15;
      #pragma unroll
      for (int kk = 0; kk < 8; ++kk)
        af[m][kk] = *(const bf16x8*)(A + arow * 256 + kk * 32 + g * 8);
    }
    if (rt == 0) __syncthreads();

    f32x4 acc[2][4] = {};
    #pragma unroll
    for (int kk = 0; kk < 8; ++kk) {
      bf16x8 bfr[4];
      #pragma unroll
      for (int n = 0; n < 4; ++n) {
        int col = n * 16 + r15;
        int lcq = kk * 4 + g;
        int s = (lcq & 24) | ((lcq ^ col) & 7);
        bfr[n] = *(const bf16x8*)&sB[col * 256 + s * 8];
      }
      #pragma unroll
      for (int m = 0; m < 2; ++m)
        #pragma unroll
        for (int n = 0; n < 4; ++n)
          acc[m][n] = __builtin_amdgcn_mfma_f32_16x16x32_bf16(af[m][kk], bfr[n], acc[m][n], 0, 0, 0);
    }

    // epilogue (r4-verbatim scalar form)
    #pragma unroll
    for (int m = 0; m < 2; ++m) {
      const int row0 = (int)brow + w * 32 + m * 16 + g * 4;
      #pragma unroll
      for (int n = 0; n < 4; ++n) {
        const int col = bcol + n * 16 + r15;
        #pragma unroll
        for (int rr = 0; rr < 4; ++rr) {
          float v = acc[m][n][rr];
          const size_t orow = (size_t)(row0 + rr);
          if (EPI == 0) {
            if (cg < NCG / 4) v *= 0.17677669529663687f * LOG2E;  // q
            else if (cg >= (NCG * 3) / 4)                         // gate
              v = 1.0f / (1.0f + __expf(-(v + gb[n])));
            Cbf[orow * 1024 + col] = f2bf(v);
          } else {
            v += bo[n];
            float gg = bf2f(gate[orow * 1024 + col]);
            Cf[orow * 256 + col] = msa[orow * 256 + col] + gg * v;
          }
        }
      }
    }
  }
}

// --------------------------------------------------------- attention
// (r10-verbatim: passing, barrier-free loop.) 2048 blocks, XCD-aware h=blk&7.
// Block = 128 q rows, 4 waves x 32 q. Swapped QK^T (mfma(K,Q) -> S^T) keeps P
// in registers; pack2bf builds PV A-operand; V LDS key order permuted at
// staging; lane-local softmax denominator.
__global__ __launch_bounds__(256) void attn_kernel(
    const u16* __restrict__ qkvg, const u16* __restrict__ biasQ,
    u16* __restrict__ attn_out)
{
  __shared__ u16 sVt[32 * 264];      // V^T, padded rows, permuted key order
  const int blk = blockIdx.x;
  const int h = blk & 7;             // head == XCD
  const int idx2 = blk >> 3;
  const int qh = idx2 & 1;
  const int b = idx2 >> 1;
  const int tid = threadIdx.x, lane = tid & 63, w = tid >> 6;
  const int g = lane >> 4, r15 = lane & 15;
  const size_t rowbase = (size_t)b * 256;
  const int qbase = qh * 128;

  {
    const int nl = (tid >> 4) & 3, q4 = tid & 15;
    const int pos = (tid >> 6) * 64 + (nl >> 1) * 32 + (q4 >> 2) * 8 + (nl & 1) * 4 + (q4 & 3);
    const uint4* vr4 = (const uint4*)(qkvg + (rowbase + tid) * 1024 + 512 + h * 32);
    #pragma unroll
    for (int c = 0; c < 4; ++c) {
      uint4 vv = vr4[c];
      unsigned uu[4] = {vv.x, vv.y, vv.z, vv.w};
      #pragma unroll
      for (int p = 0; p < 4; ++p) {
        sVt[(c * 8 + p * 2    ) * 264 + pos] = (u16)(uu[p] & 0xffffu);
        sVt[(c * 8 + p * 2 + 1) * 264 + pos] = (u16)(uu[p] >> 16);
      }
    }
  }

  const int qrel0 = qbase + w * 32 + r15;
  bf16x8 qf[2];
  #pragma unroll
  for (int m = 0; m < 2; ++m)
    qf[m] = *(const bf16x8*)(qkvg + (rowbase + qrel0 + m * 16) * 1024 + h * 32 + g * 8);
  __syncthreads();

  f32x4 oacc[2][2] = {};
  float lrun[2] = {0.f, 0.f};
  const u16* biasH = biasQ + (size_t)h * 65536;

  bf16x8 kf[4];
  ushort4 bvu[2][4];
  #pragma unroll
  for (int n = 0; n < 4; ++n)
    kf[n] = *(const bf16x8*)(qkvg + (rowbase + n * 16 + r15) * 1024 + 256 + h * 32 + g * 8);
  #pragma unroll
  for (int m = 0; m < 2; ++m)
    #pragma unroll
    for (int n = 0; n < 4; ++n)
      bvu[m][n] = *(const ushort4*)(biasH + (size_t)(qrel0 + m * 16) * 256 + n * 16 + g * 4);

  for (int jb = 0; jb < 4; ++jb) {
    f32x4 s[2][4];
    #pragma unroll
    for (int m = 0; m < 2; ++m) {
      #pragma unroll
      for (int n = 0; n < 4; ++n) {
        f32x4 z = {0.f, 0.f, 0.f, 0.f};
        s[m][n] = __builtin_amdgcn_mfma_f32_16x16x32_bf16(kf[n], qf[m], z, 0, 0, 0);
        const u16* bb = (const u16*)&bvu[m][n];
        #pragma unroll
        for (int rr = 0; rr < 4; ++rr) s[m][n][rr] += bf2f(bb[rr]);
      }
    }
    if (jb < 3) {
      const int j1 = jb + 1;
      #pragma unroll
      for (int n = 0; n < 4; ++n)
        kf[n] = *(const bf16x8*)(qkvg + (rowbase + j1 * 64 + n * 16 + r15) * 1024 + 256 + h * 32 + g * 8);
      #pragma unroll
      for (int m = 0; m < 2; ++m)
        #pragma unroll
        for (int n = 0; n < 4; ++n)
          bvu[m][n] = *(const ushort4*)(biasH + (size_t)(qrel0 + m * 16) * 256 + j1 * 64 + n * 16 + g * 4);
    }
    unsigned pk[2][4][2];
    #pragma unroll
    for (int m = 0; m < 2; ++m) {
      #pragma unroll
      for (int n = 0; n < 4; ++n) {
        #pragma unroll
        for (int rr = 0; rr < 4; ++rr) {
          float p = __builtin_amdgcn_exp2f(s[m][n][rr]);
          s[m][n][rr] = p;
          lrun[m] += p;
        }
        pk[m][n][0] = pack2bf(s[m][n][0], s[m][n][1]);
        pk[m][n][1] = pack2bf(s[m][n][2], s[m][n][3]);
      }
    }
    #pragma unroll
    for (int kb = 0; kb < 2; ++kb) {
      bf16x8 vt[2];
      #pragma unroll
      for (int nd = 0; nd < 2; ++nd)
        vt[nd] = *(const bf16x8*)&sVt[(nd * 16 + r15) * 264 + jb * 64 + kb * 32 + g * 8];
      #pragma unroll
      for (int m = 0; m < 2; ++m) {
        union { unsigned u[4]; bf16x8 v; } pu;
        pu.u[0] = pk[m][2 * kb][0];     pu.u[1] = pk[m][2 * kb][1];
        pu.u[2] = pk[m][2 * kb + 1][0]; pu.u[3] = pk[m][2 * kb + 1][1];
        #pragma unroll
        for (int nd = 0; nd < 2; ++nd)
          oacc[m][nd] = __builtin_amdgcn_mfma_f32_16x16x32_bf16(pu.v, vt[nd], oacc[m][nd], 0, 0, 0);
      }
    }
  }

  #pragma unroll
  for (int m = 0; m < 2; ++m) {
    float l = lrun[m];
    l += __shfl_xor(l, 16);
    l += __shfl_xor(l, 32);
    const float inv = 1.0f / l;
    #pragma unroll
    for (int rr = 0; rr < 4; ++rr) {
      const float invq = __shfl(inv, g * 4 + rr);
      const size_t qrow = rowbase + qbase + w * 32 + m * 16 + g * 4 + rr;
      #pragma unroll
      for (int nd = 0; nd < 2; ++nd)
        attn_out[qrow * 256 + h * 32 + nd * 16 + r15] = f2bf(oacc[m][nd][rr] * invq);
    }
  }
}

// ------------------------------------------------------------------- launcher
extern "C" void kernel_launch(void* const* d_in, const int* in_sizes, int n_in,
                              void* d_out, int out_size, void* d_ws, size_t ws_size,
                              hipStream_t stream)
{
  (void)in_sizes; (void)n_in; (void)out_size; (void)ws_size;
  const float* msa        = (const float*)d_in[0];
  const float* pair       = (const float*)d_in[1];
  const float* ln_m_scale = (const float*)d_in[2];
  const float* ln_m_bias  = (const float*)d_in[3];
  const float* ln_z_scale = (const float*)d_in[4];
  const float* ln_z_bias  = (const float*)d_in[5];
  const float* w_q        = (const float*)d_in[6];
  const float* w_k        = (const float*)d_in[7];
  const float* w_v        = (const float*)d_in[8];
  const float* w_b        = (const float*)d_in[9];
  const float* w_out      = (const float*)d_in[10];
  const float* b_out      = (const float*)d_in[11];
  const float* w_gate     = (const float*)d_in[12];
  const float* b_gate     = (const float*)d_in[13];

  char* ws = (char*)d_ws;
  u16*   m_bf   = (u16*)(ws);                    // 32768*256 bf16   = 16 MB
  u16*   wcat   = (u16*)(ws + 16777216);         // 1024*256 bf16    = 0.5 MB
  u16*   wobf   = (u16*)(ws + 17301504);         // 256*256 bf16
  u16*   qkvg   = (u16*)(ws + 17432576);         // 32768*1024 bf16  = 64 MB
  u16*   biasQ  = (u16*)(ws + 84541440);         // 8*256*256 bf16   = 1 MB
  u16*   attn_o = (u16*)(ws + 86638592);         // 32768*256 bf16   = 16 MB
  float* out = (float*)d_out;

  cast_w_kernel<<<dim3(320), dim3(256), 0, stream>>>(w_q, w_k, w_v, w_gate, w_out, wcat, wobf);
  ln_msa_kernel<<<dim3(8192), dim3(256), 0, stream>>>(msa, ln_m_scale, ln_m_bias, m_bf);
  ln_pair_bias_kernel<<<dim3(16384), dim3(256), 0, stream>>>(pair, ln_z_scale, ln_z_bias, w_b, biasQ);
  gemm_bstat<0, 16, 2><<<dim3(2048), dim3(256), 0, stream>>>(m_bf, wcat, qkvg, b_gate,
                                                             nullptr, nullptr, nullptr, nullptr);
  attn_kernel<<<dim3(2048), dim3(256), 0, stream>>>(qkvg, biasQ, attn_o);
  gemm_bstat<1, 4, 1><<<dim3(1024), dim3(256), 0, stream>>>(attn_o, wobf, nullptr, nullptr,
                                                            out, msa, qkvg + 768, b_out);
}

// Round 12
// 184.376 us; speedup vs baseline: 1.3609x; 1.0861x over previous
//
#include <hip/hip_runtime.h>

typedef unsigned short u16;
typedef float f32x4 __attribute__((ext_vector_type(4)));
typedef __bf16 bf16x8 __attribute__((ext_vector_type(8)));

__device__ __forceinline__ u16 f2bf(float f) {
  union { float f; unsigned u; } v; v.f = f;
  unsigned r = (v.u + 0x7fffu + ((v.u >> 16) & 1u)) >> 16;
  return (u16)r;
}
__device__ __forceinline__ float bf2f(u16 h) {
  union { unsigned u; float f; } v; v.u = ((unsigned)h) << 16; return v.f;
}
// pack two f32 -> one u32 of 2x bf16 (lo=a, hi=b) in pure C (no ISA assumption)
__device__ __forceinline__ unsigned pack2bf(float a, float b) {
  return ((unsigned)f2bf(b) << 16) | (unsigned)f2bf(a);
}

#define GLOAD16(gp, lp)                                                        \
  __builtin_amdgcn_global_load_lds(                                            \
      (const __attribute__((address_space(1))) void*)(gp),                     \
      (__attribute__((address_space(3))) void*)(lp), 16, 0, 0)

#define LOG2E 1.4426950408889634f

// ---------------------------------------------------------------- cast weights
__global__ __launch_bounds__(256) void cast_w_kernel(
    const float* __restrict__ wq, const float* __restrict__ wk,
    const float* __restrict__ wv, const float* __restrict__ wg,
    const float* __restrict__ wo, u16* __restrict__ wcat, u16* __restrict__ wobf)
{
  int idx = blockIdx.x * 256 + threadIdx.x;   // 320 blocks -> 81920 threads
  int e = idx * 4;                            // 4 floats each
  int row = e >> 8;
  int col = e & 255;
  const float* src = (row < 256)  ? (wq + (size_t)row * 256)
                   : (row < 512)  ? (wk + (size_t)(row - 256) * 256)
                   : (row < 768)  ? (wv + (size_t)(row - 512) * 256)
                   : (row < 1024) ? (wg + (size_t)(row - 768) * 256)
                                  : (wo + (size_t)(row - 1024) * 256);
  float4 v = *(const float4*)(src + col);
  ushort4 o;
  o.x = f2bf(v.x); o.y = f2bf(v.y); o.z = f2bf(v.z); o.w = f2bf(v.w);
  if (row < 1024) *(ushort4*)(wcat + e) = o;
  else            *(ushort4*)(wobf + (e - 262144)) = o;
}

// ---------------------------------------------------------------- LN(msa)->bf16
__global__ __launch_bounds__(256) void ln_msa_kernel(
    const float* __restrict__ x, const float* __restrict__ sc,
    const float* __restrict__ bi, u16* __restrict__ mo)
{
  const int row  = blockIdx.x * 4 + (threadIdx.x >> 6);
  const int lane = threadIdx.x & 63;
  const float4 v = *(const float4*)(x + (size_t)row * 256 + lane * 4);
  float s = v.x + v.y + v.z + v.w;
  #pragma unroll
  for (int off = 1; off < 64; off <<= 1) s += __shfl_xor(s, off);
  const float mu = s * 0.00390625f;
  const float d0 = v.x - mu, d1 = v.y - mu, d2 = v.z - mu, d3 = v.w - mu;
  float vs = d0*d0 + d1*d1 + d2*d2 + d3*d3;
  #pragma unroll
  for (int off = 1; off < 64; off <<= 1) vs += __shfl_xor(vs, off);
  const float rstd = rsqrtf(vs * 0.00390625f + 1e-5f);
  const float4 scv = *(const float4*)(sc + lane * 4);
  const float4 biv = *(const float4*)(bi + lane * 4);
  ushort4 o;
  o.x = f2bf(d0 * rstd * scv.x + biv.x);
  o.y = f2bf(d1 * rstd * scv.y + biv.y);
  o.z = f2bf(d2 * rstd * scv.z + biv.z);
  o.w = f2bf(d3 * rstd * scv.w + biv.w);
  *(ushort4*)(mo + (size_t)row * 256 + lane * 4) = o;
}

// ------------------------------------------- LN(pair) + einsum('ijc,hc->hij')
// Writes bias NATURAL layout, bf16, pre-scaled by log2(e): biasQ[h][i=q][j=key]
__global__ __launch_bounds__(256) void ln_pair_bias_kernel(
    const float* __restrict__ pair, const float* __restrict__ sc,
    const float* __restrict__ bi, const float* __restrict__ wb,
    u16* __restrict__ biasQ)
{
  __shared__ float swb[1024];
  #pragma unroll
  for (int i = 0; i < 4; ++i) swb[i * 256 + threadIdx.x] = wb[i * 256 + threadIdx.x];
  __syncthreads();
  const int ij   = blockIdx.x * 4 + (threadIdx.x >> 6);   // 0..65535
  const int lane = threadIdx.x & 63;
  const float2 v = *(const float2*)(pair + (size_t)ij * 128 + lane * 2);
  float s = v.x + v.y;
  #pragma unroll
  for (int off = 1; off < 64; off <<= 1) s += __shfl_xor(s, off);
  const float mu = s * 0.0078125f;
  const float d0 = v.x - mu, d1 = v.y - mu;
  float vs = d0*d0 + d1*d1;
  #pragma unroll
  for (int off = 1; off < 64; off <<= 1) vs += __shfl_xor(vs, off);
  const float rstd = rsqrtf(vs * 0.0078125f + 1e-5f);
  const float2 scv = *(const float2*)(sc + lane * 2);
  const float2 biv = *(const float2*)(bi + lane * 2);
  const float z0 = d0 * rstd * scv.x + biv.x;
  const float z1 = d1 * rstd * scv.y + biv.y;
  float a[8];
  #pragma unroll
  for (int hh = 0; hh < 8; ++hh)
    a[hh] = z0 * swb[hh * 128 + lane * 2] + z1 * swb[hh * 128 + lane * 2 + 1];
  #pragma unroll
  for (int off = 1; off < 64; off <<= 1) {
    #pragma unroll
    for (int hh = 0; hh < 8; ++hh) a[hh] += __shfl_xor(a[hh], off);
  }
  if (lane == 0) {
    const int i = ij >> 8, j = ij & 255;
    #pragma unroll
    for (int hh = 0; hh < 8; ++hh) biasQ[hh * 65536 + i * 256 + j] = f2bf(a[hh] * LOG2E);
  }
}

// ----------------------------------------------- B-stationary small-K GEMM
// r11 structure with two changes: __launch_bounds__(256,4) (VGPR cap 128 so
// af[2][8]+acc stay fully live -> all 16 A-loads issue in ONE batch before the
// barrier, single latency exposure) and UNITS=1 (shortest per-block chain,
// 2x blocks in flight). B tile staged once via swizzled global_load_lds.
// EPI 0: qkvg epilogue (scale q by log2e/sqrt32, sigmoid gate); EPI 1: residual
template<int EPI, int NCG, int UNITS>
__global__ __launch_bounds__(256, 4) void gemm_bstat(
    const u16* __restrict__ A, const u16* __restrict__ B,
    u16* __restrict__ Cbf, const float* __restrict__ bgate,
    float* __restrict__ Cf, const float* __restrict__ msa,
    const u16* __restrict__ gate, const float* __restrict__ bout)
{
  __shared__ u16 sB[64 * 256];   // 32 KB, XOR-swizzled within 128B groups
  const int tid = threadIdx.x, lane = tid & 63, w = tid >> 6;
  const int g = lane >> 4, r15 = lane & 15;
  const int x = blockIdx.x & 7;           // XCD
  const int j = blockIdx.x >> 3;
  const int cg = j % NCG;                 // col-group (fast-varying on an XCD)
  const int rpl = j / NCG;                // local row-group on this XCD
  const int bcol = cg * 64;

  // stage B tile; source pre-swizzled so linear LDS dest + XOR read match
  #pragma unroll
  for (int i = 0; i < 8; ++i) {
    int c = i * 256 + tid;                // chunk 0..2047 (16B each)
    int col = c >> 5, s = c & 31;
    int lc = (s & 24) | ((s ^ col) & 7);  // logical chunk stored at slot s
    GLOAD16(B + (size_t)(bcol + col) * 256 + lc * 8, &sB[c * 8]);
  }

  // hoisted epilogue constants
  float gb[4] = {0.f, 0.f, 0.f, 0.f};
  if (EPI == 0 && cg >= (NCG * 3) / 4) {
    #pragma unroll
    for (int n = 0; n < 4; ++n) gb[n] = bgate[bcol - 768 + n * 16 + r15];
  }
  float bo[4] = {0.f, 0.f, 0.f, 0.f};
  if (EPI == 1) {
    #pragma unroll
    for (int n = 0; n < 4; ++n) bo[n] = bout[bcol + n * 16 + r15];
  }

  for (int rt = 0; rt < UNITS; ++rt) {
    const size_t brow = ((size_t)(x * 32) + rpl * UNITS + rt) * 128;
    // A fragments direct from global, ALL issued before the barrier (rt=0):
    // latency hides under the B-stage vmcnt drain; 128-VGPR cap keeps them live
    bf16x8 af[2][8];
    #pragma unroll
    for (int m = 0; m < 2; ++m) {
      const size_t arow = brow + w * 32 + m * 16 + r15;
      #pragma unroll
      for (int kk = 0; kk < 8; ++kk)
        af[m][kk] = *(const bf16x8*)(A + arow * 256 + kk * 32 + g * 8);
    }
    if (rt == 0) __syncthreads();

    f32x4 acc[2][4] = {};
    #pragma unroll
    for (int kk = 0; kk < 8; ++kk) {
      bf16x8 bfr[4];
      #pragma unroll
      for (int n = 0; n < 4; ++n) {
        int col = n * 16 + r15;
        int lcq = kk * 4 + g;
        int s = (lcq & 24) | ((lcq ^ col) & 7);
        bfr[n] = *(const bf16x8*)&sB[col * 256 + s * 8];
      }
      #pragma unroll
      for (int m = 0; m < 2; ++m)
        #pragma unroll
        for (int n = 0; n < 4; ++n)
          acc[m][n] = __builtin_amdgcn_mfma_f32_16x16x32_bf16(af[m][kk], bfr[n], acc[m][n], 0, 0, 0);
    }

    // epilogue (r4-verbatim scalar form)
    #pragma unroll
    for (int m = 0; m < 2; ++m) {
      const int row0 = (int)brow + w * 32 + m * 16 + g * 4;
      #pragma unroll
      for (int n = 0; n < 4; ++n) {
        const int col = bcol + n * 16 + r15;
        #pragma unroll
        for (int rr = 0; rr < 4; ++rr) {
          float v = acc[m][n][rr];
          const size_t orow = (size_t)(row0 + rr);
          if (EPI == 0) {
            if (cg < NCG / 4) v *= 0.17677669529663687f * LOG2E;  // q
            else if (cg >= (NCG * 3) / 4)                         // gate
              v = 1.0f / (1.0f + __expf(-(v + gb[n])));
            Cbf[orow * 1024 + col] = f2bf(v);
          } else {
            v += bo[n];
            float gg = bf2f(gate[orow * 1024 + col]);
            Cf[orow * 256 + col] = msa[orow * 256 + col] + gg * v;
          }
        }
      }
    }
  }
}

// --------------------------------------------------------- attention
// (r10-verbatim: passing, barrier-free loop.) 2048 blocks, XCD-aware h=blk&7.
// Block = 128 q rows, 4 waves x 32 q. Swapped QK^T (mfma(K,Q) -> S^T) keeps P
// in registers; pack2bf builds PV A-operand; V LDS key order permuted at
// staging; lane-local softmax denominator.
__global__ __launch_bounds__(256) void attn_kernel(
    const u16* __restrict__ qkvg, const u16* __restrict__ biasQ,
    u16* __restrict__ attn_out)
{
  __shared__ u16 sVt[32 * 264];      // V^T, padded rows, permuted key order
  const int blk = blockIdx.x;
  const int h = blk & 7;             // head == XCD
  const int idx2 = blk >> 3;
  const int qh = idx2 & 1;
  const int b = idx2 >> 1;
  const int tid = threadIdx.x, lane = tid & 63, w = tid >> 6;
  const int g = lane >> 4, r15 = lane & 15;
  const size_t rowbase = (size_t)b * 256;
  const int qbase = qh * 128;

  {
    const int nl = (tid >> 4) & 3, q4 = tid & 15;
    const int pos = (tid >> 6) * 64 + (nl >> 1) * 32 + (q4 >> 2) * 8 + (nl & 1) * 4 + (q4 & 3);
    const uint4* vr4 = (const uint4*)(qkvg + (rowbase + tid) * 1024 + 512 + h * 32);
    #pragma unroll
    for (int c = 0; c < 4; ++c) {
      uint4 vv = vr4[c];
      unsigned uu[4] = {vv.x, vv.y, vv.z, vv.w};
      #pragma unroll
      for (int p = 0; p < 4; ++p) {
        sVt[(c * 8 + p * 2    ) * 264 + pos] = (u16)(uu[p] & 0xffffu);
        sVt[(c * 8 + p * 2 + 1) * 264 + pos] = (u16)(uu[p] >> 16);
      }
    }
  }

  const int qrel0 = qbase + w * 32 + r15;
  bf16x8 qf[2];
  #pragma unroll
  for (int m = 0; m < 2; ++m)
    qf[m] = *(const bf16x8*)(qkvg + (rowbase + qrel0 + m * 16) * 1024 + h * 32 + g * 8);
  __syncthreads();

  f32x4 oacc[2][2] = {};
  float lrun[2] = {0.f, 0.f};
  const u16* biasH = biasQ + (size_t)h * 65536;

  bf16x8 kf[4];
  ushort4 bvu[2][4];
  #pragma unroll
  for (int n = 0; n < 4; ++n)
    kf[n] = *(const bf16x8*)(qkvg + (rowbase + n * 16 + r15) * 1024 + 256 + h * 32 + g * 8);
  #pragma unroll
  for (int m = 0; m < 2; ++m)
    #pragma unroll
    for (int n = 0; n < 4; ++n)
      bvu[m][n] = *(const ushort4*)(biasH + (size_t)(qrel0 + m * 16) * 256 + n * 16 + g * 4);

  for (int jb = 0; jb < 4; ++jb) {
    f32x4 s[2][4];
    #pragma unroll
    for (int m = 0; m < 2; ++m) {
      #pragma unroll
      for (int n = 0; n < 4; ++n) {
        f32x4 z = {0.f, 0.f, 0.f, 0.f};
        s[m][n] = __builtin_amdgcn_mfma_f32_16x16x32_bf16(kf[n], qf[m], z, 0, 0, 0);
        const u16* bb = (const u16*)&bvu[m][n];
        #pragma unroll
        for (int rr = 0; rr < 4; ++rr) s[m][n][rr] += bf2f(bb[rr]);
      }
    }
    if (jb < 3) {
      const int j1 = jb + 1;
      #pragma unroll
      for (int n = 0; n < 4; ++n)
        kf[n] = *(const bf16x8*)(qkvg + (rowbase + j1 * 64 + n * 16 + r15) * 1024 + 256 + h * 32 + g * 8);
      #pragma unroll
      for (int m = 0; m < 2; ++m)
        #pragma unroll
        for (int n = 0; n < 4; ++n)
          bvu[m][n] = *(const ushort4*)(biasH + (size_t)(qrel0 + m * 16) * 256 + j1 * 64 + n * 16 + g * 4);
    }
    unsigned pk[2][4][2];
    #pragma unroll
    for (int m = 0; m < 2; ++m) {
      #pragma unroll
      for (int n = 0; n < 4; ++n) {
        #pragma unroll
        for (int rr = 0; rr < 4; ++rr) {
          float p = __builtin_amdgcn_exp2f(s[m][n][rr]);
          s[m][n][rr] = p;
          lrun[m] += p;
        }
        pk[m][n][0] = pack2bf(s[m][n][0], s[m][n][1]);
        pk[m][n][1] = pack2bf(s[m][n][2], s[m][n][3]);
      }
    }
    #pragma unroll
    for (int kb = 0; kb < 2; ++kb) {
      bf16x8 vt[2];
      #pragma unroll
      for (int nd = 0; nd < 2; ++nd)
        vt[nd] = *(const bf16x8*)&sVt[(nd * 16 + r15) * 264 + jb * 64 + kb * 32 + g * 8];
      #pragma unroll
      for (int m = 0; m < 2; ++m) {
        union { unsigned u[4]; bf16x8 v; } pu;
        pu.u[0] = pk[m][2 * kb][0];     pu.u[1] = pk[m][2 * kb][1];
        pu.u[2] = pk[m][2 * kb + 1][0]; pu.u[3] = pk[m][2 * kb + 1][1];
        #pragma unroll
        for (int nd = 0; nd < 2; ++nd)
          oacc[m][nd] = __builtin_amdgcn_mfma_f32_16x16x32_bf16(pu.v, vt[nd], oacc[m][nd], 0, 0, 0);
      }
    }
  }

  #pragma unroll
  for (int m = 0; m < 2; ++m) {
    float l = lrun[m];
    l += __shfl_xor(l, 16);
    l += __shfl_xor(l, 32);
    const float inv = 1.0f / l;
    #pragma unroll
    for (int rr = 0; rr < 4; ++rr) {
      const float invq = __shfl(inv, g * 4 + rr);
      const size_t qrow = rowbase + qbase + w * 32 + m * 16 + g * 4 + rr;
      #pragma unroll
      for (int nd = 0; nd < 2; ++nd)
        attn_out[qrow * 256 + h * 32 + nd * 16 + r15] = f2bf(oacc[m][nd][rr] * invq);
    }
  }
}

// ------------------------------------------------------------------- launcher
extern "C" void kernel_launch(void* const* d_in, const int* in_sizes, int n_in,
                              void* d_out, int out_size, void* d_ws, size_t ws_size,
                              hipStream_t stream)
{
  (void)in_sizes; (void)n_in; (void)out_size; (void)ws_size;
  const float* msa        = (const float*)d_in[0];
  const float* pair       = (const float*)d_in[1];
  const float* ln_m_scale = (const float*)d_in[2];
  const float* ln_m_bias  = (const float*)d_in[3];
  const float* ln_z_scale = (const float*)d_in[4];
  const float* ln_z_bias  = (const float*)d_in[5];
  const float* w_q        = (const float*)d_in[6];
  const float* w_k        = (const float*)d_in[7];
  const float* w_v        = (const float*)d_in[8];
  const float* w_b        = (const float*)d_in[9];
  const float* w_out      = (const float*)d_in[10];
  const float* b_out      = (const float*)d_in[11];
  const float* w_gate     = (const float*)d_in[12];
  const float* b_gate     = (const float*)d_in[13];

  char* ws = (char*)d_ws;
  u16*   m_bf   = (u16*)(ws);                    // 32768*256 bf16   = 16 MB
  u16*   wcat   = (u16*)(ws + 16777216);         // 1024*256 bf16    = 0.5 MB
  u16*   wobf   = (u16*)(ws + 17301504);         // 256*256 bf16
  u16*   qkvg   = (u16*)(ws + 17432576);         // 32768*1024 bf16  = 64 MB
  u16*   biasQ  = (u16*)(ws + 84541440);         // 8*256*256 bf16   = 1 MB
  u16*   attn_o = (u16*)(ws + 86638592);         // 32768*256 bf16   = 16 MB
  float* out = (float*)d_out;

  cast_w_kernel<<<dim3(320), dim3(256), 0, stream>>>(w_q, w_k, w_v, w_gate, w_out, wcat, wobf);
  ln_msa_kernel<<<dim3(8192), dim3(256), 0, stream>>>(msa, ln_m_scale, ln_m_bias, m_bf);
  ln_pair_bias_kernel<<<dim3(16384), dim3(256), 0, stream>>>(pair, ln_z_scale, ln_z_bias, w_b, biasQ);
  gemm_bstat<0, 16, 1><<<dim3(4096), dim3(256), 0, stream>>>(m_bf, wcat, qkvg, b_gate,
                                                             nullptr, nullptr, nullptr, nullptr);
  attn_kernel<<<dim3(2048), dim3(256), 0, stream>>>(qkvg, biasQ, attn_o);
  gemm_bstat<1, 4, 1><<<dim3(1024), dim3(256), 0, stream>>>(attn_o, wobf, nullptr, nullptr,
                                                            out, msa, qkvg + 768, b_out);
}

// Round 13
// 177.855 us; speedup vs baseline: 1.4108x; 1.0367x over previous
//
#include <hip/hip_runtime.h>

typedef unsigned short u16;
typedef float f32x4 __attribute__((ext_vector_type(4)));
typedef __bf16 bf16x8 __attribute__((ext_vector_type(8)));

__device__ __forceinline__ u16 f2bf(float f) {
  union { float f; unsigned u; } v; v.f = f;
  unsigned r = (v.u + 0x7fffu + ((v.u >> 16) & 1u)) >> 16;
  return (u16)r;
}
__device__ __forceinline__ float bf2f(u16 h) {
  union { unsigned u; float f; } v; v.u = ((unsigned)h) << 16; return v.f;
}

#define GLOAD16(gp, lp)                                                        \
  __builtin_amdgcn_global_load_lds(                                            \
      (const __attribute__((address_space(1))) void*)(gp),                     \
      (__attribute__((address_space(3))) void*)(lp), 16, 0, 0)

#define LOG2E 1.4426950408889634f
#define HS 1048576   // per-head plane: 32768 rows * 32

// ---------------------------------------------------------------- cast weights
__global__ __launch_bounds__(256) void cast_w_kernel(
    const float* __restrict__ wq, const float* __restrict__ wk,
    const float* __restrict__ wv, const float* __restrict__ wg,
    const float* __restrict__ wo, u16* __restrict__ wcat, u16* __restrict__ wobf)
{
  int idx = blockIdx.x * 256 + threadIdx.x;   // 320 blocks -> 81920 threads
  int e = idx * 4;                            // 4 floats each
  int row = e >> 8;
  int col = e & 255;
  const float* src = (row < 256)  ? (wq + (size_t)row * 256)
                   : (row < 512)  ? (wk + (size_t)(row - 256) * 256)
                   : (row < 768)  ? (wv + (size_t)(row - 512) * 256)
                   : (row < 1024) ? (wg + (size_t)(row - 768) * 256)
                                  : (wo + (size_t)(row - 1024) * 256);
  float4 v = *(const float4*)(src + col);
  ushort4 o;
  o.x = f2bf(v.x); o.y = f2bf(v.y); o.z = f2bf(v.z); o.w = f2bf(v.w);
  if (row < 1024) *(ushort4*)(wcat + e) = o;
  else            *(ushort4*)(wobf + (e - 262144)) = o;
}

// ---------------------------------------------------------------- LN(msa)->bf16
__global__ __launch_bounds__(256) void ln_msa_kernel(
    const float* __restrict__ x, const float* __restrict__ sc,
    const float* __restrict__ bi, u16* __restrict__ mo)
{
  const int row  = blockIdx.x * 4 + (threadIdx.x >> 6);
  const int lane = threadIdx.x & 63;
  const float4 v = *(const float4*)(x + (size_t)row * 256 + lane * 4);
  float s = v.x + v.y + v.z + v.w;
  #pragma unroll
  for (int off = 1; off < 64; off <<= 1) s += __shfl_xor(s, off);
  const float mu = s * 0.00390625f;
  const float d0 = v.x - mu, d1 = v.y - mu, d2 = v.z - mu, d3 = v.w - mu;
  float vs = d0*d0 + d1*d1 + d2*d2 + d3*d3;
  #pragma unroll
  for (int off = 1; off < 64; off <<= 1) vs += __shfl_xor(vs, off);
  const float rstd = rsqrtf(vs * 0.00390625f + 1e-5f);
  const float4 scv = *(const float4*)(sc + lane * 4);
  const float4 biv = *(const float4*)(bi + lane * 4);
  ushort4 o;
  o.x = f2bf(d0 * rstd * scv.x + biv.x);
  o.y = f2bf(d1 * rstd * scv.y + biv.y);
  o.z = f2bf(d2 * rstd * scv.z + biv.z);
  o.w = f2bf(d3 * rstd * scv.w + biv.w);
  *(ushort4*)(mo + (size_t)row * 256 + lane * 4) = o;
}

// ------------------------------------------- LN(pair) + einsum('ijc,hc->hij')
// Writes bias NATURAL layout, bf16, pre-scaled by log2(e): biasQ[h][i=q][j=key]
__global__ __launch_bounds__(256) void ln_pair_bias_kernel(
    const float* __restrict__ pair, const float* __restrict__ sc,
    const float* __restrict__ bi, const float* __restrict__ wb,
    u16* __restrict__ biasQ)
{
  __shared__ float swb[1024];
  #pragma unroll
  for (int i = 0; i < 4; ++i) swb[i * 256 + threadIdx.x] = wb[i * 256 + threadIdx.x];
  __syncthreads();
  const int ij   = blockIdx.x * 4 + (threadIdx.x >> 6);   // 0..65535
  const int lane = threadIdx.x & 63;
  const float2 v = *(const float2*)(pair + (size_t)ij * 128 + lane * 2);
  float s = v.x + v.y;
  #pragma unroll
  for (int off = 1; off < 64; off <<= 1) s += __shfl_xor(s, off);
  const float mu = s * 0.0078125f;
  const float d0 = v.x - mu, d1 = v.y - mu;
  float vs = d0*d0 + d1*d1;
  #pragma unroll
  for (int off = 1; off < 64; off <<= 1) vs += __shfl_xor(vs, off);
  const float rstd = rsqrtf(vs * 0.0078125f + 1e-5f);
  const float2 scv = *(const float2*)(sc + lane * 2);
  const float2 biv = *(const float2*)(bi + lane * 2);
  const float z0 = d0 * rstd * scv.x + biv.x;
  const float z1 = d1 * rstd * scv.y + biv.y;
  float a[8];
  #pragma unroll
  for (int hh = 0; hh < 8; ++hh)
    a[hh] = z0 * swb[hh * 128 + lane * 2] + z1 * swb[hh * 128 + lane * 2 + 1];
  #pragma unroll
  for (int off = 1; off < 64; off <<= 1) {
    #pragma unroll
    for (int hh = 0; hh < 8; ++hh) a[hh] += __shfl_xor(a[hh], off);
  }
  if (lane == 0) {
    const int i = ij >> 8, j = ij & 255;
    #pragma unroll
    for (int hh = 0; hh < 8; ++hh) biasQ[hh * 65536 + i * 256 + j] = f2bf(a[hh] * LOG2E);
  }
}

// ----------------------------------------------- B-stationary small-K GEMM
// r12 structure (the verified champion: launch_bounds(256,4), UNITS=1).
// EPI 0: writes HEAD-BLOCKED outputs: Qh/Kh/Vh [8][32768][32] (+q-scale,
//        sigmoid gate -> gateb [32768][256]) so attention loads coalesce.
// EPI 1: residual epilogue, gate read from gateb.
template<int EPI, int NCG>
__global__ __launch_bounds__(256, 4) void gemm_bstat(
    const u16* __restrict__ A, const u16* __restrict__ B,
    u16* __restrict__ qh, u16* __restrict__ kh, u16* __restrict__ vh,
    u16* __restrict__ gateb, const float* __restrict__ bgate,
    float* __restrict__ Cf, const float* __restrict__ msa,
    const float* __restrict__ bout)
{
  __shared__ u16 sB[64 * 256];   // 32 KB, XOR-swizzled within 128B groups
  const int tid = threadIdx.x, lane = tid & 63, w = tid >> 6;
  const int g = lane >> 4, r15 = lane & 15;
  const int x = blockIdx.x & 7;           // XCD
  const int j = blockIdx.x >> 3;
  const int cg = j % NCG;                 // col-group (fast-varying on an XCD)
  const int rpl = j / NCG;                // local row-group on this XCD
  const int bcol = cg * 64;

  // stage B tile; source pre-swizzled so linear LDS dest + XOR read match
  #pragma unroll
  for (int i = 0; i < 8; ++i) {
    int c = i * 256 + tid;                // chunk 0..2047 (16B each)
    int col = c >> 5, s = c & 31;
    int lc = (s & 24) | ((s ^ col) & 7);  // logical chunk stored at slot s
    GLOAD16(B + (size_t)(bcol + col) * 256 + lc * 8, &sB[c * 8]);
  }

  // hoisted epilogue constants
  float gb[4] = {0.f, 0.f, 0.f, 0.f};
  if (EPI == 0 && cg >= (NCG * 3) / 4) {
    #pragma unroll
    for (int n = 0; n < 4; ++n) gb[n] = bgate[bcol - 768 + n * 16 + r15];
  }
  float bo[4] = {0.f, 0.f, 0.f, 0.f};
  if (EPI == 1) {
    #pragma unroll
    for (int n = 0; n < 4; ++n) bo[n] = bout[bcol + n * 16 + r15];
  }

  const size_t brow = ((size_t)(x * 32) + rpl) * 128;
  // A fragments direct from global, ALL issued before the barrier: latency
  // hides under the B-stage vmcnt drain; 128-VGPR cap keeps them live
  bf16x8 af[2][8];
  #pragma unroll
  for (int m = 0; m < 2; ++m) {
    const size_t arow = brow + w * 32 + m * 16 + r15;
    #pragma unroll
    for (int kk = 0; kk < 8; ++kk)
      af[m][kk] = *(const bf16x8*)(A + arow * 256 + kk * 32 + g * 8);
  }
  __syncthreads();

  f32x4 acc[2][4] = {};
  #pragma unroll
  for (int kk = 0; kk < 8; ++kk) {
    bf16x8 bfr[4];
    #pragma unroll
    for (int n = 0; n < 4; ++n) {
      int col = n * 16 + r15;
      int lcq = kk * 4 + g;
      int s = (lcq & 24) | ((lcq ^ col) & 7);
      bfr[n] = *(const bf16x8*)&sB[col * 256 + s * 8];
    }
    #pragma unroll
    for (int m = 0; m < 2; ++m)
      #pragma unroll
      for (int n = 0; n < 4; ++n)
        acc[m][n] = __builtin_amdgcn_mfma_f32_16x16x32_bf16(af[m][kk], bfr[n], acc[m][n], 0, 0, 0);
  }

  #pragma unroll
  for (int m = 0; m < 2; ++m) {
    const int row0 = (int)brow + w * 32 + m * 16 + g * 4;
    #pragma unroll
    for (int n = 0; n < 4; ++n) {
      const int col = bcol + n * 16 + r15;
      #pragma unroll
      for (int rr = 0; rr < 4; ++rr) {
        float v = acc[m][n][rr];
        const size_t orow = (size_t)(row0 + rr);
        if (EPI == 0) {
          if (col < 256) {                               // q -> head-blocked
            v *= 0.17677669529663687f * LOG2E;
            qh[(size_t)(col >> 5) * HS + orow * 32 + (col & 31)] = f2bf(v);
          } else if (col < 512) {                        // k
            const int c = col - 256;
            kh[(size_t)(c >> 5) * HS + orow * 32 + (c & 31)] = f2bf(v);
          } else if (col < 768) {                        // v
            const int c = col - 512;
            vh[(size_t)(c >> 5) * HS + orow * 32 + (c & 31)] = f2bf(v);
          } else {                                       // gate (sigmoid)
            v = 1.0f / (1.0f + __expf(-(v + gb[n])));
            gateb[orow * 256 + (col - 768)] = f2bf(v);
          }
        } else {
          v += bo[n];
          float gg = bf2f(gateb[orow * 256 + col]);
          Cf[orow * 256 + col] = msa[orow * 256 + col] + gg * v;
        }
      }
    }
  }
}

// --------------------------------------------------------- attention
// Head-blocked inputs Qh/Kh/Vh [8][32768][32]: ALL loads coalesced now.
// 2048 blocks, XCD-aware h=blk&7. Block = 128 q rows, 4 waves x 32 q.
// Swapped QK^T (mfma(K,Q) -> S^T) keeps P in registers; NATIVE __bf16 casts
// (compiler emits v_cvt_pk_bf16_f32) build PV A-operand; V LDS key order
// permuted at staging; lane-local softmax denominator.
__global__ __launch_bounds__(256) void attn_kernel(
    const u16* __restrict__ qh, const u16* __restrict__ kh,
    const u16* __restrict__ vh, const u16* __restrict__ biasQ,
    u16* __restrict__ attn_out)
{
  __shared__ u16 sVt[32 * 264];      // V^T, padded rows, permuted key order
  const int blk = blockIdx.x;
  const int h = blk & 7;             // head == XCD
  const int idx2 = blk >> 3;
  const int qh_i = idx2 & 1;
  const int b = idx2 >> 1;
  const int tid = threadIdx.x, lane = tid & 63, w = tid >> 6;
  const int g = lane >> 4, r15 = lane & 15;
  const size_t rowbase = (size_t)b * 256;
  const int qbase = qh_i * 128;

  const u16* Qh = qh + (size_t)h * HS;
  const u16* Kh = kh + (size_t)h * HS;
  const u16* Vh = vh + (size_t)h * HS;

  // stage V^T from coalesced Vh rows; key tid stored at permuted column pos so
  // that position kb*32 + g*8 + jj holds key kb*32 + (jj>>2)*16 + g*4 + (jj&3)
  {
    const int nl = (tid >> 4) & 3, q4 = tid & 15;
    const int pos = (tid >> 6) * 64 + (nl >> 1) * 32 + (q4 >> 2) * 8 + (nl & 1) * 4 + (q4 & 3);
    const uint4* vr4 = (const uint4*)(Vh + (rowbase + tid) * 32);
    #pragma unroll
    for (int c = 0; c < 4; ++c) {
      uint4 vv = vr4[c];
      unsigned uu[4] = {vv.x, vv.y, vv.z, vv.w};
      #pragma unroll
      for (int p = 0; p < 4; ++p) {
        sVt[(c * 8 + p * 2    ) * 264 + pos] = (u16)(uu[p] & 0xffffu);
        sVt[(c * 8 + p * 2 + 1) * 264 + pos] = (u16)(uu[p] >> 16);
      }
    }
  }

  const int qrel0 = qbase + w * 32 + r15;
  bf16x8 qf[2];
  #pragma unroll
  for (int m = 0; m < 2; ++m)
    qf[m] = *(const bf16x8*)(Qh + (rowbase + qrel0 + m * 16) * 32 + g * 8);
  __syncthreads();

  f32x4 oacc[2][2] = {};
  float lrun[2] = {0.f, 0.f};
  const u16* biasH = biasQ + (size_t)h * 65536;

  bf16x8 kf[4];
  ushort4 bvu[2][4];
  #pragma unroll
  for (int n = 0; n < 4; ++n)
    kf[n] = *(const bf16x8*)(Kh + (rowbase + n * 16 + r15) * 32 + g * 8);
  #pragma unroll
  for (int m = 0; m < 2; ++m)
    #pragma unroll
    for (int n = 0; n < 4; ++n)
      bvu[m][n] = *(const ushort4*)(biasH + (size_t)(qrel0 + m * 16) * 256 + n * 16 + g * 4);

  for (int jb = 0; jb < 4; ++jb) {
    // S^T = K.Q^T: lane holds S[q = qrel0 + m*16][key = jb*64 + n*16 + g*4 + rr]
    f32x4 s[2][4];
    #pragma unroll
    for (int m = 0; m < 2; ++m) {
      #pragma unroll
      for (int n = 0; n < 4; ++n) {
        f32x4 z = {0.f, 0.f, 0.f, 0.f};
        s[m][n] = __builtin_amdgcn_mfma_f32_16x16x32_bf16(kf[n], qf[m], z, 0, 0, 0);
        const u16* bb = (const u16*)&bvu[m][n];
        #pragma unroll
        for (int rr = 0; rr < 4; ++rr) s[m][n][rr] += bf2f(bb[rr]);
      }
    }
    if (jb < 3) {
      const int j1 = jb + 1;
      #pragma unroll
      for (int n = 0; n < 4; ++n)
        kf[n] = *(const bf16x8*)(Kh + (rowbase + j1 * 64 + n * 16 + r15) * 32 + g * 8);
      #pragma unroll
      for (int m = 0; m < 2; ++m)
        #pragma unroll
        for (int n = 0; n < 4; ++n)
          bvu[m][n] = *(const ushort4*)(biasH + (size_t)(qrel0 + m * 16) * 256 + j1 * 64 + n * 16 + g * 4);
    }
    // P = exp2(S): lane-local denominator
    #pragma unroll
    for (int m = 0; m < 2; ++m)
      #pragma unroll
      for (int n = 0; n < 4; ++n)
        #pragma unroll
        for (int rr = 0; rr < 4; ++rr) {
          float p = __builtin_amdgcn_exp2f(s[m][n][rr]);
          s[m][n][rr] = p;
          lrun[m] += p;
        }
    // PV: native __bf16 casts build the A-operand (cvt_pk); V in matching order
    #pragma unroll
    for (int kb = 0; kb < 2; ++kb) {
      bf16x8 vt[2];
      #pragma unroll
      for (int nd = 0; nd < 2; ++nd)
        vt[nd] = *(const bf16x8*)&sVt[(nd * 16 + r15) * 264 + jb * 64 + kb * 32 + g * 8];
      #pragma unroll
      for (int m = 0; m < 2; ++m) {
        bf16x8 pv;
        #pragma unroll
        for (int rr = 0; rr < 4; ++rr) {
          pv[rr]     = (__bf16)s[m][2 * kb][rr];
          pv[4 + rr] = (__bf16)s[m][2 * kb + 1][rr];
        }
        #pragma unroll
        for (int nd = 0; nd < 2; ++nd)
          oacc[m][nd] = __builtin_amdgcn_mfma_f32_16x16x32_bf16(pv, vt[nd], oacc[m][nd], 0, 0, 0);
      }
    }
  }

  #pragma unroll
  for (int m = 0; m < 2; ++m) {
    float l = lrun[m];
    l += __shfl_xor(l, 16);
    l += __shfl_xor(l, 32);
    const float inv = 1.0f / l;
    #pragma unroll
    for (int rr = 0; rr < 4; ++rr) {
      const float invq = __shfl(inv, g * 4 + rr);
      const size_t qrow = rowbase + qbase + w * 32 + m * 16 + g * 4 + rr;
      #pragma unroll
      for (int nd = 0; nd < 2; ++nd)
        attn_out[qrow * 256 + h * 32 + nd * 16 + r15] = f2bf(oacc[m][nd][rr] * invq);
    }
  }
}

// ------------------------------------------------------------------- launcher
extern "C" void kernel_launch(void* const* d_in, const int* in_sizes, int n_in,
                              void* d_out, int out_size, void* d_ws, size_t ws_size,
                              hipStream_t stream)
{
  (void)in_sizes; (void)n_in; (void)out_size; (void)ws_size;
  const float* msa        = (const float*)d_in[0];
  const float* pair       = (const float*)d_in[1];
  const float* ln_m_scale = (const float*)d_in[2];
  const float* ln_m_bias  = (const float*)d_in[3];
  const float* ln_z_scale = (const float*)d_in[4];
  const float* ln_z_bias  = (const float*)d_in[5];
  const float* w_q        = (const float*)d_in[6];
  const float* w_k        = (const float*)d_in[7];
  const float* w_v        = (const float*)d_in[8];
  const float* w_b        = (const float*)d_in[9];
  const float* w_out      = (const float*)d_in[10];
  const float* b_out      = (const float*)d_in[11];
  const float* w_gate     = (const float*)d_in[12];
  const float* b_gate     = (const float*)d_in[13];

  char* ws = (char*)d_ws;
  u16*   m_bf   = (u16*)(ws);                    // 32768*256 bf16   = 16 MB
  u16*   wcat   = (u16*)(ws + 16777216);         // 1024*256 bf16    = 0.5 MB
  u16*   wobf   = (u16*)(ws + 17301504);         // 256*256 bf16
  u16*   qh     = (u16*)(ws + 17432576);         // 8*32768*32 bf16  = 16 MB
  u16*   kh     = (u16*)(ws + 34209792);         // 16 MB
  u16*   vh     = (u16*)(ws + 50987008);         // 16 MB
  u16*   gateb  = (u16*)(ws + 67764224);         // 32768*256 bf16   = 16 MB
  u16*   biasQ  = (u16*)(ws + 84541440);         // 8*256*256 bf16   = 1 MB
  u16*   attn_o = (u16*)(ws + 86638592);         // 32768*256 bf16   = 16 MB
  float* out = (float*)d_out;

  cast_w_kernel<<<dim3(320), dim3(256), 0, stream>>>(w_q, w_k, w_v, w_gate, w_out, wcat, wobf);
  ln_msa_kernel<<<dim3(8192), dim3(256), 0, stream>>>(msa, ln_m_scale, ln_m_bias, m_bf);
  ln_pair_bias_kernel<<<dim3(16384), dim3(256), 0, stream>>>(pair, ln_z_scale, ln_z_bias, w_b, biasQ);
  gemm_bstat<0, 16><<<dim3(4096), dim3(256), 0, stream>>>(m_bf, wcat, qh, kh, vh, gateb,
                                                          b_gate, nullptr, nullptr, nullptr);
  attn_kernel<<<dim3(2048), dim3(256), 0, stream>>>(qh, kh, vh, biasQ, attn_o);
  gemm_bstat<1, 4><<<dim3(1024), dim3(256), 0, stream>>>(attn_o, wobf, nullptr, nullptr, nullptr,
                                                         gateb, nullptr, out, msa, b_out);
}

// Round 14
// 170.467 us; speedup vs baseline: 1.4719x; 1.0433x over previous
//
#include <hip/hip_runtime.h>

typedef unsigned short u16;
typedef float f32x4 __attribute__((ext_vector_type(4)));
typedef __bf16 bf16x8 __attribute__((ext_vector_type(8)));

__device__ __forceinline__ u16 f2bf(float f) {
  union { float f; unsigned u; } v; v.f = f;
  unsigned r = (v.u + 0x7fffu + ((v.u >> 16) & 1u)) >> 16;
  return (u16)r;
}
__device__ __forceinline__ float bf2f(u16 h) {
  union { unsigned u; float f; } v; v.u = ((unsigned)h) << 16; return v.f;
}

#define GLOAD16(gp, lp)                                                        \
  __builtin_amdgcn_global_load_lds(                                            \
      (const __attribute__((address_space(1))) void*)(gp),                     \
      (__attribute__((address_space(3))) void*)(lp), 16, 0, 0)

#define LOG2E 1.4426950408889634f
#define HS 1048576   // per-head plane: 32768 rows * 32

// --------------------------- fat pre-kernel: LN(msa) ++ cast weights
// blocks [0,8192): LN rows; blocks [8192,8512): weight cast. Independent work,
// one launch boundary saved; both memory-bound.
__global__ __launch_bounds__(256) void pre_kernel(
    const float* __restrict__ x, const float* __restrict__ sc,
    const float* __restrict__ bi, u16* __restrict__ mo,
    const float* __restrict__ wq, const float* __restrict__ wk,
    const float* __restrict__ wv, const float* __restrict__ wg,
    const float* __restrict__ wo, u16* __restrict__ wcat, u16* __restrict__ wobf)
{
  if (blockIdx.x < 8192) {
    const int row  = blockIdx.x * 4 + (threadIdx.x >> 6);
    const int lane = threadIdx.x & 63;
    const float4 v = *(const float4*)(x + (size_t)row * 256 + lane * 4);
    float s = v.x + v.y + v.z + v.w;
    #pragma unroll
    for (int off = 1; off < 64; off <<= 1) s += __shfl_xor(s, off);
    const float mu = s * 0.00390625f;
    const float d0 = v.x - mu, d1 = v.y - mu, d2 = v.z - mu, d3 = v.w - mu;
    float vs = d0*d0 + d1*d1 + d2*d2 + d3*d3;
    #pragma unroll
    for (int off = 1; off < 64; off <<= 1) vs += __shfl_xor(vs, off);
    const float rstd = rsqrtf(vs * 0.00390625f + 1e-5f);
    const float4 scv = *(const float4*)(sc + lane * 4);
    const float4 biv = *(const float4*)(bi + lane * 4);
    ushort4 o;
    o.x = f2bf(d0 * rstd * scv.x + biv.x);
    o.y = f2bf(d1 * rstd * scv.y + biv.y);
    o.z = f2bf(d2 * rstd * scv.z + biv.z);
    o.w = f2bf(d3 * rstd * scv.w + biv.w);
    *(ushort4*)(mo + (size_t)row * 256 + lane * 4) = o;
  } else {
    int idx = (blockIdx.x - 8192) * 256 + threadIdx.x;
    int e = idx * 4;
    int row = e >> 8;
    int col = e & 255;
    const float* src = (row < 256)  ? (wq + (size_t)row * 256)
                     : (row < 512)  ? (wk + (size_t)(row - 256) * 256)
                     : (row < 768)  ? (wv + (size_t)(row - 512) * 256)
                     : (row < 1024) ? (wg + (size_t)(row - 768) * 256)
                                    : (wo + (size_t)(row - 1024) * 256);
    float4 v = *(const float4*)(src + col);
    ushort4 o;
    o.x = f2bf(v.x); o.y = f2bf(v.y); o.z = f2bf(v.z); o.w = f2bf(v.w);
    if (row < 1024) *(ushort4*)(wcat + e) = o;
    else            *(ushort4*)(wobf + (e - 262144)) = o;
  }
}

// --------------------------- fat kernel 0: GEMM(qkvg, EPI0) ++ LN(pair)+bias
// blocks [0,4096): r13-verbatim B-stationary GEMM writing head-blocked
// Qh/Kh/Vh + sigmoid gate. blocks [4096,20480): pair-LN + bias einsum,
// backfilling the GEMM's idle memory/VALU slots (pair-LN is independent of
// the GEMM; both feed the NEXT launch). smem shared: sB (32 KB) / swb (4 KB).
__global__ __launch_bounds__(256, 4) void fat0_kernel(
    const u16* __restrict__ A, const u16* __restrict__ B,
    u16* __restrict__ qhp, u16* __restrict__ khp, u16* __restrict__ vhp,
    u16* __restrict__ gateb, const float* __restrict__ bgate,
    const float* __restrict__ pair, const float* __restrict__ scz,
    const float* __restrict__ biz, const float* __restrict__ wb,
    u16* __restrict__ biasQ)
{
  __shared__ u16 smem[64 * 256];   // 32 KB
  const int tid = threadIdx.x, lane = tid & 63;

  if (blockIdx.x < 4096) {
    // ---------------- GEMM EPI0 (r13-verbatim) ----------------
    u16* sB = smem;
    const int w = tid >> 6;
    const int g = lane >> 4, r15 = lane & 15;
    const int x = blockIdx.x & 7;           // XCD
    const int j = blockIdx.x >> 3;
    const int cg = j % 16;                  // col-group (fast-varying on XCD)
    const int rpl = j / 16;                 // local row-group
    const int bcol = cg * 64;

    #pragma unroll
    for (int i = 0; i < 8; ++i) {
      int c = i * 256 + tid;
      int col = c >> 5, s = c & 31;
      int lc = (s & 24) | ((s ^ col) & 7);
      GLOAD16(B + (size_t)(bcol + col) * 256 + lc * 8, &sB[c * 8]);
    }

    float gb[4] = {0.f, 0.f, 0.f, 0.f};
    if (cg >= 12) {
      #pragma unroll
      for (int n = 0; n < 4; ++n) gb[n] = bgate[bcol - 768 + n * 16 + r15];
    }

    const size_t brow = ((size_t)(x * 32) + rpl) * 128;
    bf16x8 af[2][8];
    #pragma unroll
    for (int m = 0; m < 2; ++m) {
      const size_t arow = brow + w * 32 + m * 16 + r15;
      #pragma unroll
      for (int kk = 0; kk < 8; ++kk)
        af[m][kk] = *(const bf16x8*)(A + arow * 256 + kk * 32 + g * 8);
    }
    __syncthreads();

    f32x4 acc[2][4] = {};
    #pragma unroll
    for (int kk = 0; kk < 8; ++kk) {
      bf16x8 bfr[4];
      #pragma unroll
      for (int n = 0; n < 4; ++n) {
        int col = n * 16 + r15;
        int lcq = kk * 4 + g;
        int s = (lcq & 24) | ((lcq ^ col) & 7);
        bfr[n] = *(const bf16x8*)&sB[col * 256 + s * 8];
      }
      #pragma unroll
      for (int m = 0; m < 2; ++m)
        #pragma unroll
        for (int n = 0; n < 4; ++n)
          acc[m][n] = __builtin_amdgcn_mfma_f32_16x16x32_bf16(af[m][kk], bfr[n], acc[m][n], 0, 0, 0);
    }

    #pragma unroll
    for (int m = 0; m < 2; ++m) {
      const int row0 = (int)brow + w * 32 + m * 16 + g * 4;
      #pragma unroll
      for (int n = 0; n < 4; ++n) {
        const int col = bcol + n * 16 + r15;
        #pragma unroll
        for (int rr = 0; rr < 4; ++rr) {
          float v = acc[m][n][rr];
          const size_t orow = (size_t)(row0 + rr);
          if (col < 256) {                               // q -> head-blocked
            v *= 0.17677669529663687f * LOG2E;
            qhp[(size_t)(col >> 5) * HS + orow * 32 + (col & 31)] = f2bf(v);
          } else if (col < 512) {                        // k
            const int c = col - 256;
            khp[(size_t)(c >> 5) * HS + orow * 32 + (c & 31)] = f2bf(v);
          } else if (col < 768) {                        // v
            const int c = col - 512;
            vhp[(size_t)(c >> 5) * HS + orow * 32 + (c & 31)] = f2bf(v);
          } else {                                       // gate (sigmoid)
            v = 1.0f / (1.0f + __expf(-(v + gb[n])));
            gateb[orow * 256 + (col - 768)] = f2bf(v);
          }
        }
      }
    }
  } else {
    // ---------------- LN(pair) + einsum (r13-verbatim body) ----------------
    float* swb = (float*)smem;
    #pragma unroll
    for (int i = 0; i < 4; ++i) swb[i * 256 + tid] = wb[i * 256 + tid];
    __syncthreads();
    const int ij = (blockIdx.x - 4096) * 4 + (tid >> 6);   // 0..65535
    const float2 v = *(const float2*)(pair + (size_t)ij * 128 + lane * 2);
    float s = v.x + v.y;
    #pragma unroll
    for (int off = 1; off < 64; off <<= 1) s += __shfl_xor(s, off);
    const float mu = s * 0.0078125f;
    const float d0 = v.x - mu, d1 = v.y - mu;
    float vs = d0*d0 + d1*d1;
    #pragma unroll
    for (int off = 1; off < 64; off <<= 1) vs += __shfl_xor(vs, off);
    const float rstd = rsqrtf(vs * 0.0078125f + 1e-5f);
    const float2 scv = *(const float2*)(scz + lane * 2);
    const float2 biv = *(const float2*)(biz + lane * 2);
    const float z0 = d0 * rstd * scv.x + biv.x;
    const float z1 = d1 * rstd * scv.y + biv.y;
    float a[8];
    #pragma unroll
    for (int hh = 0; hh < 8; ++hh)
      a[hh] = z0 * swb[hh * 128 + lane * 2] + z1 * swb[hh * 128 + lane * 2 + 1];
    #pragma unroll
    for (int off = 1; off < 64; off <<= 1) {
      #pragma unroll
      for (int hh = 0; hh < 8; ++hh) a[hh] += __shfl_xor(a[hh], off);
    }
    if (lane == 0) {
      const int i = ij >> 8, jj = ij & 255;
      #pragma unroll
      for (int hh = 0; hh < 8; ++hh) biasQ[hh * 65536 + i * 256 + jj] = f2bf(a[hh] * LOG2E);
    }
  }
}

// ----------------------------------------------- EPI1 GEMM (r13-verbatim)
__global__ __launch_bounds__(256, 4) void gemm_epi1(
    const u16* __restrict__ A, const u16* __restrict__ B,
    const u16* __restrict__ gateb, float* __restrict__ Cf,
    const float* __restrict__ msa, const float* __restrict__ bout)
{
  __shared__ u16 sB[64 * 256];
  const int tid = threadIdx.x, lane = tid & 63, w = tid >> 6;
  const int g = lane >> 4, r15 = lane & 15;
  const int x = blockIdx.x & 7;
  const int j = blockIdx.x >> 3;
  const int cg = j % 4;
  const int rpl = j / 4;
  const int bcol = cg * 64;

  #pragma unroll
  for (int i = 0; i < 8; ++i) {
    int c = i * 256 + tid;
    int col = c >> 5, s = c & 31;
    int lc = (s & 24) | ((s ^ col) & 7);
    GLOAD16(B + (size_t)(bcol + col) * 256 + lc * 8, &sB[c * 8]);
  }

  float bo[4];
  #pragma unroll
  for (int n = 0; n < 4; ++n) bo[n] = bout[bcol + n * 16 + r15];

  const size_t brow = ((size_t)(x * 32) + rpl) * 128;
  bf16x8 af[2][8];
  #pragma unroll
  for (int m = 0; m < 2; ++m) {
    const size_t arow = brow + w * 32 + m * 16 + r15;
    #pragma unroll
    for (int kk = 0; kk < 8; ++kk)
      af[m][kk] = *(const bf16x8*)(A + arow * 256 + kk * 32 + g * 8);
  }
  __syncthreads();

  f32x4 acc[2][4] = {};
  #pragma unroll
  for (int kk = 0; kk < 8; ++kk) {
    bf16x8 bfr[4];
    #pragma unroll
    for (int n = 0; n < 4; ++n) {
      int col = n * 16 + r15;
      int lcq = kk * 4 + g;
      int s = (lcq & 24) | ((lcq ^ col) & 7);
      bfr[n] = *(const bf16x8*)&sB[col * 256 + s * 8];
    }
    #pragma unroll
    for (int m = 0; m < 2; ++m)
      #pragma unroll
      for (int n = 0; n < 4; ++n)
        acc[m][n] = __builtin_amdgcn_mfma_f32_16x16x32_bf16(af[m][kk], bfr[n], acc[m][n], 0, 0, 0);
  }

  #pragma unroll
  for (int m = 0; m < 2; ++m) {
    const int row0 = (int)brow + w * 32 + m * 16 + g * 4;
    #pragma unroll
    for (int n = 0; n < 4; ++n) {
      const int col = bcol + n * 16 + r15;
      #pragma unroll
      for (int rr = 0; rr < 4; ++rr) {
        float v = acc[m][n][rr] + bo[n];
        const size_t orow = (size_t)(row0 + rr);
        float gg = bf2f(gateb[orow * 256 + col]);
        Cf[orow * 256 + col] = msa[orow * 256 + col] + gg * v;
      }
    }
  }
}

// --------------------------------------------------------- attention
// (r13-verbatim.) Head-blocked Qh/Kh/Vh; 2048 blocks, XCD-aware h=blk&7;
// swapped QK^T keeps P in registers; native __bf16 casts; permuted V staging;
// lane-local softmax denominator.
__global__ __launch_bounds__(256) void attn_kernel(
    const u16* __restrict__ qh, const u16* __restrict__ kh,
    const u16* __restrict__ vh, const u16* __restrict__ biasQ,
    u16* __restrict__ attn_out)
{
  __shared__ u16 sVt[32 * 264];
  const int blk = blockIdx.x;
  const int h = blk & 7;
  const int idx2 = blk >> 3;
  const int qh_i = idx2 & 1;
  const int b = idx2 >> 1;
  const int tid = threadIdx.x, lane = tid & 63, w = tid >> 6;
  const int g = lane >> 4, r15 = lane & 15;
  const size_t rowbase = (size_t)b * 256;
  const int qbase = qh_i * 128;

  const u16* Qh = qh + (size_t)h * HS;
  const u16* Kh = kh + (size_t)h * HS;
  const u16* Vh = vh + (size_t)h * HS;

  {
    const int nl = (tid >> 4) & 3, q4 = tid & 15;
    const int pos = (tid >> 6) * 64 + (nl >> 1) * 32 + (q4 >> 2) * 8 + (nl & 1) * 4 + (q4 & 3);
    const uint4* vr4 = (const uint4*)(Vh + (rowbase + tid) * 32);
    #pragma unroll
    for (int c = 0; c < 4; ++c) {
      uint4 vv = vr4[c];
      unsigned uu[4] = {vv.x, vv.y, vv.z, vv.w};
      #pragma unroll
      for (int p = 0; p < 4; ++p) {
        sVt[(c * 8 + p * 2    ) * 264 + pos] = (u16)(uu[p] & 0xffffu);
        sVt[(c * 8 + p * 2 + 1) * 264 + pos] = (u16)(uu[p] >> 16);
      }
    }
  }

  const int qrel0 = qbase + w * 32 + r15;
  bf16x8 qf[2];
  #pragma unroll
  for (int m = 0; m < 2; ++m)
    qf[m] = *(const bf16x8*)(Qh + (rowbase + qrel0 + m * 16) * 32 + g * 8);
  __syncthreads();

  f32x4 oacc[2][2] = {};
  float lrun[2] = {0.f, 0.f};
  const u16* biasH = biasQ + (size_t)h * 65536;

  bf16x8 kf[4];
  ushort4 bvu[2][4];
  #pragma unroll
  for (int n = 0; n < 4; ++n)
    kf[n] = *(const bf16x8*)(Kh + (rowbase + n * 16 + r15) * 32 + g * 8);
  #pragma unroll
  for (int m = 0; m < 2; ++m)
    #pragma unroll
    for (int n = 0; n < 4; ++n)
      bvu[m][n] = *(const ushort4*)(biasH + (size_t)(qrel0 + m * 16) * 256 + n * 16 + g * 4);

  for (int jb = 0; jb < 4; ++jb) {
    f32x4 s[2][4];
    #pragma unroll
    for (int m = 0; m < 2; ++m) {
      #pragma unroll
      for (int n = 0; n < 4; ++n) {
        f32x4 z = {0.f, 0.f, 0.f, 0.f};
        s[m][n] = __builtin_amdgcn_mfma_f32_16x16x32_bf16(kf[n], qf[m], z, 0, 0, 0);
        const u16* bb = (const u16*)&bvu[m][n];
        #pragma unroll
        for (int rr = 0; rr < 4; ++rr) s[m][n][rr] += bf2f(bb[rr]);
      }
    }
    if (jb < 3) {
      const int j1 = jb + 1;
      #pragma unroll
      for (int n = 0; n < 4; ++n)
        kf[n] = *(const bf16x8*)(Kh + (rowbase + j1 * 64 + n * 16 + r15) * 32 + g * 8);
      #pragma unroll
      for (int m = 0; m < 2; ++m)
        #pragma unroll
        for (int n = 0; n < 4; ++n)
          bvu[m][n] = *(const ushort4*)(biasH + (size_t)(qrel0 + m * 16) * 256 + j1 * 64 + n * 16 + g * 4);
    }
    #pragma unroll
    for (int m = 0; m < 2; ++m)
      #pragma unroll
      for (int n = 0; n < 4; ++n)
        #pragma unroll
        for (int rr = 0; rr < 4; ++rr) {
          float p = __builtin_amdgcn_exp2f(s[m][n][rr]);
          s[m][n][rr] = p;
          lrun[m] += p;
        }
    #pragma unroll
    for (int kb = 0; kb < 2; ++kb) {
      bf16x8 vt[2];
      #pragma unroll
      for (int nd = 0; nd < 2; ++nd)
        vt[nd] = *(const bf16x8*)&sVt[(nd * 16 + r15) * 264 + jb * 64 + kb * 32 + g * 8];
      #pragma unroll
      for (int m = 0; m < 2; ++m) {
        bf16x8 pv;
        #pragma unroll
        for (int rr = 0; rr < 4; ++rr) {
          pv[rr]     = (__bf16)s[m][2 * kb][rr];
          pv[4 + rr] = (__bf16)s[m][2 * kb + 1][rr];
        }
        #pragma unroll
        for (int nd = 0; nd < 2; ++nd)
          oacc[m][nd] = __builtin_amdgcn_mfma_f32_16x16x32_bf16(pv, vt[nd], oacc[m][nd], 0, 0, 0);
      }
    }
  }

  #pragma unroll
  for (int m = 0; m < 2; ++m) {
    float l = lrun[m];
    l += __shfl_xor(l, 16);
    l += __shfl_xor(l, 32);
    const float inv = 1.0f / l;
    #pragma unroll
    for (int rr = 0; rr < 4; ++rr) {
      const float invq = __shfl(inv, g * 4 + rr);
      const size_t qrow = rowbase + qbase + w * 32 + m * 16 + g * 4 + rr;
      #pragma unroll
      for (int nd = 0; nd < 2; ++nd)
        attn_out[qrow * 256 + h * 32 + nd * 16 + r15] = f2bf(oacc[m][nd][rr] * invq);
    }
  }
}

// ------------------------------------------------------------------- launcher
extern "C" void kernel_launch(void* const* d_in, const int* in_sizes, int n_in,
                              void* d_out, int out_size, void* d_ws, size_t ws_size,
                              hipStream_t stream)
{
  (void)in_sizes; (void)n_in; (void)out_size; (void)ws_size;
  const float* msa        = (const float*)d_in[0];
  const float* pair       = (const float*)d_in[1];
  const float* ln_m_scale = (const float*)d_in[2];
  const float* ln_m_bias  = (const float*)d_in[3];
  const float* ln_z_scale = (const float*)d_in[4];
  const float* ln_z_bias  = (const float*)d_in[5];
  const float* w_q        = (const float*)d_in[6];
  const float* w_k        = (const float*)d_in[7];
  const float* w_v        = (const float*)d_in[8];
  const float* w_b        = (const float*)d_in[9];
  const float* w_out      = (const float*)d_in[10];
  const float* b_out      = (const float*)d_in[11];
  const float* w_gate     = (const float*)d_in[12];
  const float* b_gate     = (const float*)d_in[13];

  char* ws = (char*)d_ws;
  u16*   m_bf   = (u16*)(ws);                    // 32768*256 bf16   = 16 MB
  u16*   wcat   = (u16*)(ws + 16777216);         // 1024*256 bf16    = 0.5 MB
  u16*   wobf   = (u16*)(ws + 17301504);         // 256*256 bf16
  u16*   qh     = (u16*)(ws + 17432576);         // 8*32768*32 bf16  = 16 MB
  u16*   kh     = (u16*)(ws + 34209792);         // 16 MB
  u16*   vh     = (u16*)(ws + 50987008);         // 16 MB
  u16*   gateb  = (u16*)(ws + 67764224);         // 32768*256 bf16   = 16 MB
  u16*   biasQ  = (u16*)(ws + 84541440);         // 8*256*256 bf16   = 1 MB
  u16*   attn_o = (u16*)(ws + 86638592);         // 32768*256 bf16   = 16 MB
  float* out = (float*)d_out;

  pre_kernel<<<dim3(8512), dim3(256), 0, stream>>>(
      msa, ln_m_scale, ln_m_bias, m_bf, w_q, w_k, w_v, w_gate, w_out, wcat, wobf);
  fat0_kernel<<<dim3(20480), dim3(256), 0, stream>>>(
      m_bf, wcat, qh, kh, vh, gateb, b_gate,
      pair, ln_z_scale, ln_z_bias, w_b, biasQ);
  attn_kernel<<<dim3(2048), dim3(256), 0, stream>>>(qh, kh, vh, biasQ, attn_o);
  gemm_epi1<<<dim3(1024), dim3(256), 0, stream>>>(attn_o, wobf, gateb, out, msa, b_out);
}

// Round 15
// 138.697 us; speedup vs baseline: 1.8091x; 1.2291x over previous
//
#include <hip/hip_runtime.h>

typedef unsigned short u16;
typedef float f32x4 __attribute__((ext_vector_type(4)));
typedef __bf16 bf16x8 __attribute__((ext_vector_type(8)));

__device__ __forceinline__ u16 f2bf(float f) {
  union { float f; unsigned u; } v; v.f = f;
  unsigned r = (v.u + 0x7fffu + ((v.u >> 16) & 1u)) >> 16;
  return (u16)r;
}
__device__ __forceinline__ float bf2f(u16 h) {
  union { unsigned u; float f; } v; v.u = ((unsigned)h) << 16; return v.f;
}

#define GLOAD16(gp, lp)                                                        \
  __builtin_amdgcn_global_load_lds(                                            \
      (const __attribute__((address_space(1))) void*)(gp),                     \
      (__attribute__((address_space(3))) void*)(lp), 16, 0, 0)

#define LOG2E 1.4426950408889634f
#define HS 1048576   // per-head plane: 32768 rows * 32

// --------------------------- fat pre-kernel: LN(msa) ++ cast weights
__global__ __launch_bounds__(256) void pre_kernel(
    const float* __restrict__ x, const float* __restrict__ sc,
    const float* __restrict__ bi, u16* __restrict__ mo,
    const float* __restrict__ wq, const float* __restrict__ wk,
    const float* __restrict__ wv, const float* __restrict__ wg,
    const float* __restrict__ wo, u16* __restrict__ wcat, u16* __restrict__ wobf)
{
  if (blockIdx.x < 8192) {
    const int row  = blockIdx.x * 4 + (threadIdx.x >> 6);
    const int lane = threadIdx.x & 63;
    const float4 v = *(const float4*)(x + (size_t)row * 256 + lane * 4);
    float s = v.x + v.y + v.z + v.w;
    #pragma unroll
    for (int off = 1; off < 64; off <<= 1) s += __shfl_xor(s, off);
    const float mu = s * 0.00390625f;
    const float d0 = v.x - mu, d1 = v.y - mu, d2 = v.z - mu, d3 = v.w - mu;
    float vs = d0*d0 + d1*d1 + d2*d2 + d3*d3;
    #pragma unroll
    for (int off = 1; off < 64; off <<= 1) vs += __shfl_xor(vs, off);
    const float rstd = rsqrtf(vs * 0.00390625f + 1e-5f);
    const float4 scv = *(const float4*)(sc + lane * 4);
    const float4 biv = *(const float4*)(bi + lane * 4);
    ushort4 o;
    o.x = f2bf(d0 * rstd * scv.x + biv.x);
    o.y = f2bf(d1 * rstd * scv.y + biv.y);
    o.z = f2bf(d2 * rstd * scv.z + biv.z);
    o.w = f2bf(d3 * rstd * scv.w + biv.w);
    *(ushort4*)(mo + (size_t)row * 256 + lane * 4) = o;
  } else {
    int idx = (blockIdx.x - 8192) * 256 + threadIdx.x;
    int e = idx * 4;
    int row = e >> 8;
    int col = e & 255;
    const float* src = (row < 256)  ? (wq + (size_t)row * 256)
                     : (row < 512)  ? (wk + (size_t)(row - 256) * 256)
                     : (row < 768)  ? (wv + (size_t)(row - 512) * 256)
                     : (row < 1024) ? (wg + (size_t)(row - 768) * 256)
                                    : (wo + (size_t)(row - 1024) * 256);
    float4 v = *(const float4*)(src + col);
    ushort4 o;
    o.x = f2bf(v.x); o.y = f2bf(v.y); o.z = f2bf(v.z); o.w = f2bf(v.w);
    if (row < 1024) *(ushort4*)(wcat + e) = o;
    else            *(ushort4*)(wobf + (e - 262144)) = o;
  }
}

// --------------------- LN(pair)+bias einsum, closed form, shuffle-free
// bias[h] = rstd*(dot(x,swc[h]) - mu*A_h) + B_h, swc[h][c]=sc[c]*wb[h][c],
// A_h=sum_c swc, B_h=sum_c bi*wb. 2 threads per (i,j): each owns 4 heads and
// the full 128-c row (sum/ss computed redundantly). No cross-lane ops at all;
// coalesced bf16 writes (j == lane pair). swc in LDS as [c][8] -> one
// broadcast ds_read_b128 per (element, 4-head group).
__global__ __launch_bounds__(256) void ln_pair_fast(
    const float* __restrict__ pair, const float* __restrict__ sc,
    const float* __restrict__ bi, const float* __restrict__ wb,
    u16* __restrict__ biasQ)
{
  __shared__ float swc[1024];     // [c][h]
  __shared__ float sA[8], sB2[8];
  const int tid = threadIdx.x;
  #pragma unroll
  for (int k = 0; k < 4; ++k) {
    int idx = k * 256 + tid;      // idx = c*8 + h
    int c = idx >> 3, h = idx & 7;
    swc[idx] = sc[c] * wb[h * 128 + c];
  }
  __syncthreads();
  if (tid < 8) {
    float a = 0.f, b2 = 0.f;
    for (int c = 0; c < 128; ++c) {
      a  += swc[c * 8 + tid];
      b2 += bi[c] * wb[tid * 128 + c];
    }
    sA[tid] = a; sB2[tid] = b2;
  }
  __syncthreads();

  const int gt = blockIdx.x * 256 + tid;   // 131072 threads total
  const int ij = gt >> 1, hg = gt & 1;     // 2 threads per pair-row
  const float* xr = pair + (size_t)ij * 128;
  float s = 0.f, ss = 0.f;
  float d0 = 0.f, d1 = 0.f, d2 = 0.f, d3 = 0.f;
  for (int c0 = 0; c0 < 128; c0 += 4) {
    float4 xv4 = *(const float4*)(xr + c0);
    float xe[4] = {xv4.x, xv4.y, xv4.z, xv4.w};
    #pragma unroll
    for (int e = 0; e < 4; ++e) {
      const float xv = xe[e];
      s += xv; ss += xv * xv;
      const f32x4 wv = *(const f32x4*)&swc[(c0 + e) * 8 + hg * 4];
      d0 += xv * wv[0]; d1 += xv * wv[1];
      d2 += xv * wv[2]; d3 += xv * wv[3];
    }
  }
  const float mu = s * 0.0078125f;
  const float rstd = rsqrtf(ss * 0.0078125f - mu * mu + 1e-5f);
  const int i = ij >> 8, j = ij & 255;
  const float dd[4] = {d0, d1, d2, d3};
  #pragma unroll
  for (int hh = 0; hh < 4; ++hh) {
    const int h = hg * 4 + hh;
    const float bias = (dd[hh] - mu * sA[h]) * rstd + sB2[h];
    biasQ[h * 65536 + i * 256 + j] = f2bf(bias * LOG2E);
  }
}

// ----------------------------------------------- B-stationary small-K GEMM
// (r13-verbatim: launch_bounds(256,4), UNITS=1, head-blocked EPI0 outputs.)
template<int EPI, int NCG>
__global__ __launch_bounds__(256, 4) void gemm_bstat(
    const u16* __restrict__ A, const u16* __restrict__ B,
    u16* __restrict__ qh, u16* __restrict__ kh, u16* __restrict__ vh,
    u16* __restrict__ gateb, const float* __restrict__ bgate,
    float* __restrict__ Cf, const float* __restrict__ msa,
    const float* __restrict__ bout)
{
  __shared__ u16 sB[64 * 256];   // 32 KB, XOR-swizzled within 128B groups
  const int tid = threadIdx.x, lane = tid & 63, w = tid >> 6;
  const int g = lane >> 4, r15 = lane & 15;
  const int x = blockIdx.x & 7;           // XCD
  const int j = blockIdx.x >> 3;
  const int cg = j % NCG;
  const int rpl = j / NCG;
  const int bcol = cg * 64;

  #pragma unroll
  for (int i = 0; i < 8; ++i) {
    int c = i * 256 + tid;
    int col = c >> 5, s = c & 31;
    int lc = (s & 24) | ((s ^ col) & 7);
    GLOAD16(B + (size_t)(bcol + col) * 256 + lc * 8, &sB[c * 8]);
  }

  float gb[4] = {0.f, 0.f, 0.f, 0.f};
  if (EPI == 0 && cg >= (NCG * 3) / 4) {
    #pragma unroll
    for (int n = 0; n < 4; ++n) gb[n] = bgate[bcol - 768 + n * 16 + r15];
  }
  float bo[4] = {0.f, 0.f, 0.f, 0.f};
  if (EPI == 1) {
    #pragma unroll
    for (int n = 0; n < 4; ++n) bo[n] = bout[bcol + n * 16 + r15];
  }

  const size_t brow = ((size_t)(x * 32) + rpl) * 128;
  bf16x8 af[2][8];
  #pragma unroll
  for (int m = 0; m < 2; ++m) {
    const size_t arow = brow + w * 32 + m * 16 + r15;
    #pragma unroll
    for (int kk = 0; kk < 8; ++kk)
      af[m][kk] = *(const bf16x8*)(A + arow * 256 + kk * 32 + g * 8);
  }
  __syncthreads();

  f32x4 acc[2][4] = {};
  #pragma unroll
  for (int kk = 0; kk < 8; ++kk) {
    bf16x8 bfr[4];
    #pragma unroll
    for (int n = 0; n < 4; ++n) {
      int col = n * 16 + r15;
      int lcq = kk * 4 + g;
      int s = (lcq & 24) | ((lcq ^ col) & 7);
      bfr[n] = *(const bf16x8*)&sB[col * 256 + s * 8];
    }
    #pragma unroll
    for (int m = 0; m < 2; ++m)
      #pragma unroll
      for (int n = 0; n < 4; ++n)
        acc[m][n] = __builtin_amdgcn_mfma_f32_16x16x32_bf16(af[m][kk], bfr[n], acc[m][n], 0, 0, 0);
  }

  #pragma unroll
  for (int m = 0; m < 2; ++m) {
    const int row0 = (int)brow + w * 32 + m * 16 + g * 4;
    #pragma unroll
    for (int n = 0; n < 4; ++n) {
      const int col = bcol + n * 16 + r15;
      #pragma unroll
      for (int rr = 0; rr < 4; ++rr) {
        float v = acc[m][n][rr];
        const size_t orow = (size_t)(row0 + rr);
        if (EPI == 0) {
          if (col < 256) {
            v *= 0.17677669529663687f * LOG2E;
            qh[(size_t)(col >> 5) * HS + orow * 32 + (col & 31)] = f2bf(v);
          } else if (col < 512) {
            const int c = col - 256;
            kh[(size_t)(c >> 5) * HS + orow * 32 + (c & 31)] = f2bf(v);
          } else if (col < 768) {
            const int c = col - 512;
            vh[(size_t)(c >> 5) * HS + orow * 32 + (c & 31)] = f2bf(v);
          } else {
            v = 1.0f / (1.0f + __expf(-(v + gb[n])));
            gateb[orow * 256 + (col - 768)] = f2bf(v);
          }
        } else {
          v += bo[n];
          float gg = bf2f(gateb[orow * 256 + col]);
          Cf[orow * 256 + col] = msa[orow * 256 + col] + gg * v;
        }
      }
    }
  }
}

// --------------------------------------------------------- attention
// (r13-verbatim.)
__global__ __launch_bounds__(256) void attn_kernel(
    const u16* __restrict__ qh, const u16* __restrict__ kh,
    const u16* __restrict__ vh, const u16* __restrict__ biasQ,
    u16* __restrict__ attn_out)
{
  __shared__ u16 sVt[32 * 264];
  const int blk = blockIdx.x;
  const int h = blk & 7;
  const int idx2 = blk >> 3;
  const int qh_i = idx2 & 1;
  const int b = idx2 >> 1;
  const int tid = threadIdx.x, lane = tid & 63, w = tid >> 6;
  const int g = lane >> 4, r15 = lane & 15;
  const size_t rowbase = (size_t)b * 256;
  const int qbase = qh_i * 128;

  const u16* Qh = qh + (size_t)h * HS;
  const u16* Kh = kh + (size_t)h * HS;
  const u16* Vh = vh + (size_t)h * HS;

  {
    const int nl = (tid >> 4) & 3, q4 = tid & 15;
    const int pos = (tid >> 6) * 64 + (nl >> 1) * 32 + (q4 >> 2) * 8 + (nl & 1) * 4 + (q4 & 3);
    const uint4* vr4 = (const uint4*)(Vh + (rowbase + tid) * 32);
    #pragma unroll
    for (int c = 0; c < 4; ++c) {
      uint4 vv = vr4[c];
      unsigned uu[4] = {vv.x, vv.y, vv.z, vv.w};
      #pragma unroll
      for (int p = 0; p < 4; ++p) {
        sVt[(c * 8 + p * 2    ) * 264 + pos] = (u16)(uu[p] & 0xffffu);
        sVt[(c * 8 + p * 2 + 1) * 264 + pos] = (u16)(uu[p] >> 16);
      }
    }
  }

  const int qrel0 = qbase + w * 32 + r15;
  bf16x8 qf[2];
  #pragma unroll
  for (int m = 0; m < 2; ++m)
    qf[m] = *(const bf16x8*)(Qh + (rowbase + qrel0 + m * 16) * 32 + g * 8);
  __syncthreads();

  f32x4 oacc[2][2] = {};
  float lrun[2] = {0.f, 0.f};
  const u16* biasH = biasQ + (size_t)h * 65536;

  bf16x8 kf[4];
  ushort4 bvu[2][4];
  #pragma unroll
  for (int n = 0; n < 4; ++n)
    kf[n] = *(const bf16x8*)(Kh + (rowbase + n * 16 + r15) * 32 + g * 8);
  #pragma unroll
  for (int m = 0; m < 2; ++m)
    #pragma unroll
    for (int n = 0; n < 4; ++n)
      bvu[m][n] = *(const ushort4*)(biasH + (size_t)(qrel0 + m * 16) * 256 + n * 16 + g * 4);

  for (int jb = 0; jb < 4; ++jb) {
    f32x4 s[2][4];
    #pragma unroll
    for (int m = 0; m < 2; ++m) {
      #pragma unroll
      for (int n = 0; n < 4; ++n) {
        f32x4 z = {0.f, 0.f, 0.f, 0.f};
        s[m][n] = __builtin_amdgcn_mfma_f32_16x16x32_bf16(kf[n], qf[m], z, 0, 0, 0);
        const u16* bb = (const u16*)&bvu[m][n];
        #pragma unroll
        for (int rr = 0; rr < 4; ++rr) s[m][n][rr] += bf2f(bb[rr]);
      }
    }
    if (jb < 3) {
      const int j1 = jb + 1;
      #pragma unroll
      for (int n = 0; n < 4; ++n)
        kf[n] = *(const bf16x8*)(Kh + (rowbase + j1 * 64 + n * 16 + r15) * 32 + g * 8);
      #pragma unroll
      for (int m = 0; m < 2; ++m)
        #pragma unroll
        for (int n = 0; n < 4; ++n)
          bvu[m][n] = *(const ushort4*)(biasH + (size_t)(qrel0 + m * 16) * 256 + j1 * 64 + n * 16 + g * 4);
    }
    #pragma unroll
    for (int m = 0; m < 2; ++m)
      #pragma unroll
      for (int n = 0; n < 4; ++n)
        #pragma unroll
        for (int rr = 0; rr < 4; ++rr) {
          float p = __builtin_amdgcn_exp2f(s[m][n][rr]);
          s[m][n][rr] = p;
          lrun[m] += p;
        }
    #pragma unroll
    for (int kb = 0; kb < 2; ++kb) {
      bf16x8 vt[2];
      #pragma unroll
      for (int nd = 0; nd < 2; ++nd)
        vt[nd] = *(const bf16x8*)&sVt[(nd * 16 + r15) * 264 + jb * 64 + kb * 32 + g * 8];
      #pragma unroll
      for (int m = 0; m < 2; ++m) {
        bf16x8 pv;
        #pragma unroll
        for (int rr = 0; rr < 4; ++rr) {
          pv[rr]     = (__bf16)s[m][2 * kb][rr];
          pv[4 + rr] = (__bf16)s[m][2 * kb + 1][rr];
        }
        #pragma unroll
        for (int nd = 0; nd < 2; ++nd)
          oacc[m][nd] = __builtin_amdgcn_mfma_f32_16x16x32_bf16(pv, vt[nd], oacc[m][nd], 0, 0, 0);
      }
    }
  }

  #pragma unroll
  for (int m = 0; m < 2; ++m) {
    float l = lrun[m];
    l += __shfl_xor(l, 16);
    l += __shfl_xor(l, 32);
    const float inv = 1.0f / l;
    #pragma unroll
    for (int rr = 0; rr < 4; ++rr) {
      const float invq = __shfl(inv, g * 4 + rr);
      const size_t qrow = rowbase + qbase + w * 32 + m * 16 + g * 4 + rr;
      #pragma unroll
      for (int nd = 0; nd < 2; ++nd)
        attn_out[qrow * 256 + h * 32 + nd * 16 + r15] = f2bf(oacc[m][nd][rr] * invq);
    }
  }
}

// ------------------------------------------------------------------- launcher
extern "C" void kernel_launch(void* const* d_in, const int* in_sizes, int n_in,
                              void* d_out, int out_size, void* d_ws, size_t ws_size,
                              hipStream_t stream)
{
  (void)in_sizes; (void)n_in; (void)out_size; (void)ws_size;
  const float* msa        = (const float*)d_in[0];
  const float* pair       = (const float*)d_in[1];
  const float* ln_m_scale = (const float*)d_in[2];
  const float* ln_m_bias  = (const float*)d_in[3];
  const float* ln_z_scale = (const float*)d_in[4];
  const float* ln_z_bias  = (const float*)d_in[5];
  const float* w_q        = (const float*)d_in[6];
  const float* w_k        = (const float*)d_in[7];
  const float* w_v        = (const float*)d_in[8];
  const float* w_b        = (const float*)d_in[9];
  const float* w_out      = (const float*)d_in[10];
  const float* b_out      = (const float*)d_in[11];
  const float* w_gate     = (const float*)d_in[12];
  const float* b_gate     = (const float*)d_in[13];

  char* ws = (char*)d_ws;
  u16*   m_bf   = (u16*)(ws);                    // 32768*256 bf16   = 16 MB
  u16*   wcat   = (u16*)(ws + 16777216);         // 1024*256 bf16    = 0.5 MB
  u16*   wobf   = (u16*)(ws + 17301504);         // 256*256 bf16
  u16*   qh     = (u16*)(ws + 17432576);         // 8*32768*32 bf16  = 16 MB
  u16*   kh     = (u16*)(ws + 34209792);         // 16 MB
  u16*   vh     = (u16*)(ws + 50987008);         // 16 MB
  u16*   gateb  = (u16*)(ws + 67764224);         // 32768*256 bf16   = 16 MB
  u16*   biasQ  = (u16*)(ws + 84541440);         // 8*256*256 bf16   = 1 MB
  u16*   attn_o = (u16*)(ws + 86638592);         // 32768*256 bf16   = 16 MB
  float* out = (float*)d_out;

  pre_kernel<<<dim3(8512), dim3(256), 0, stream>>>(
      msa, ln_m_scale, ln_m_bias, m_bf, w_q, w_k, w_v, w_gate, w_out, wcat, wobf);
  ln_pair_fast<<<dim3(512), dim3(256), 0, stream>>>(
      pair, ln_z_scale, ln_z_bias, w_b, biasQ);
  gemm_bstat<0, 16><<<dim3(4096), dim3(256), 0, stream>>>(m_bf, wcat, qh, kh, vh, gateb,
                                                          b_gate, nullptr, nullptr, nullptr);
  attn_kernel<<<dim3(2048), dim3(256), 0, stream>>>(qh, kh, vh, biasQ, attn_o);
  gemm_bstat<1, 4><<<dim3(1024), dim3(256), 0, stream>>>(attn_o, wobf, nullptr, nullptr, nullptr,
                                                         gateb, nullptr, out, msa, b_out);
}